// Round 1
// 530.068 us; speedup vs baseline: 1.0701x; 1.0701x over previous
//
#include <hip/hip_runtime.h>
#include <math.h>

#define DD 128
#define CAPB 2048            // per-bucket capacity; mean ~1024 at E/N=16, 64-node buckets
#define MAXNB 1600           // max buckets (N <= 102400)

typedef __attribute__((ext_vector_type(8))) short bf16x8;
typedef __attribute__((ext_vector_type(4))) float f32x4;

__device__ __forceinline__ unsigned short f2bf(float f) {
    unsigned u = __float_as_uint(f);
    unsigned r = u + 0x7FFF + ((u >> 16) & 1);
    return (unsigned short)(r >> 16);
}
__device__ __forceinline__ float bf2f(unsigned short h) {
    return __uint_as_float(((unsigned)h) << 16);
}

__global__ void k_wsfail(float* __restrict__ out, float val, int n) {
    int i = blockIdx.x * 256 + threadIdx.x;
    if (i < n) out[i] = (i == 0) ? val : 0.0f;
}

// ---------------------------------------------------------------------------
// k_setup: detect + zero sums/gCur + w1T/w2T transposes + x->AGG[,256:384)
// blocks: [0]: detect+sums; [1,8): gCur; [8,136): w1T; [136,264): w2T;
//         [264, 264+ncvt): cvtx
// ---------------------------------------------------------------------------
__global__ void k_setup(const int* __restrict__ e32, int* __restrict__ flag,
                        float* __restrict__ sums, int* __restrict__ gCur, int NB,
                        const float* __restrict__ W1, const float* __restrict__ W2,
                        unsigned short* __restrict__ w1T, unsigned short* __restrict__ w2T,
                        const float* __restrict__ x, unsigned short* __restrict__ AGG,
                        int total_x) {
    const int bid = blockIdx.x;
    const int t = threadIdx.x;
    if (bid == 0) {
        if (t == 0) {
            int f = 1;
            for (int i = 1; i < 16; i += 2) f &= (e32[i] == 0);
            *flag = f;  // 1 => int64 edges
        }
        for (int i = t; i < 768; i += 256) sums[i] = 0.0f;
    } else if (bid < 8) {
        int i = (bid - 1) * 256 + t;
        if (i < NB) gCur[i] = 0;
    } else if (bid < 136) {
        int i = (bid - 8) * 256 + t;   // < 32768
        int j = i >> 7, k = i & 127;
        w1T[j * 128 + k] = f2bf(W1[k * 256 + j]);
    } else if (bid < 264) {
        int i = (bid - 136) * 256 + t; // < 32768
        int j = i >> 8, k = i & 255;
        w2T[j * 256 + k] = f2bf(W2[k * 128 + j]);
    } else {
        int idx = (bid - 264) * 256 + t;
        if (idx < total_x) {
            int i = idx >> 7, j = idx & 127;
            AGG[(size_t)i * 384 + 256 + j] = f2bf(x[idx]);
        }
    }
}

// ---------------------------------------------------------------------------
// k_fusew: fold merge-linear into gate weights (fp32 math, one bf16 rounding)
// Logical column j (0..511): [0,256)=r|z (gi+gh), [256,384)=i_n, [384,512)=h_n
// PERMUTED physical layout so each 64-col group holds all 4 gates of 16 dims:
//   pj(d,g) = (d>>4)*64 + g*16 + (d&15),  g=j>>7, d=j&127
// This makes the GRU a per-lane register op in the GEMM epilogue (nt = gate).
// BtG[pj][k] (k<384):
//   k<256:  (j<384) ? dot(Wm[k,:], Wih[j,:]) : 0
//   k>=256: j<256 ? Whh[j][k-256] : (j>=384 ? Whh[j-128][k-256] : 0)
// biasG[pj] = base_bias(j) + (j<384 ? dot(bm, Wih[j,:]) : 0)
// ---------------------------------------------------------------------------
__global__ void k_fusew(const float* __restrict__ Wm, const float* __restrict__ Wih,
                        const float* __restrict__ Whh, const float* __restrict__ bm,
                        const float* __restrict__ b_ih, const float* __restrict__ b_hh,
                        unsigned short* __restrict__ BtG, float* __restrict__ biasG) {
    const int j = blockIdx.x;
    const int c = threadIdx.x;
    const int g = j >> 7, d = j & 127;
    const int pj = ((d >> 4) << 6) + (g << 4) + (d & 15);
    float acc = 0.0f;
    if (j < 384) {
        const float* wr = Wih + (size_t)j * 128;
        const float* wc = Wm + (size_t)c * 128;
        for (int m = 0; m < 128; m++) acc += wc[m] * wr[m];
    }
    BtG[(size_t)pj * 384 + c] = f2bf(acc);
    if (c < 128) {
        float v = 0.0f;
        if (j < 256) v = Whh[(size_t)j * 128 + c];
        else if (j >= 384) v = Whh[(size_t)(j - 128) * 128 + c];
        BtG[(size_t)pj * 384 + 256 + c] = f2bf(v);
    }
    if (c == 0) {
        float b;
        if (j < 256) b = b_ih[j] + b_hh[j];
        else if (j < 384) b = b_ih[j];
        else b = b_hh[j - 128];
        if (j < 384) {
            const float* wr = Wih + (size_t)j * 128;
            float dd = 0.0f;
            for (int m = 0; m < 128; m++) dd += bm[m] * wr[m];
            b += dd;
        }
        biasG[pj] = b;
    }
}

// ---------------------------------------------------------------------------
// pass A: bin edges into per-bucket windows (bucket = dst>>6, 64 nodes)
// entry = src | (dstLocal << 23)
// ---------------------------------------------------------------------------
__global__ __launch_bounds__(256) void k_bin(const void* __restrict__ edges_raw,
                                             const int* __restrict__ flag,
                                             int* __restrict__ gCur,
                                             unsigned* __restrict__ binned,
                                             int E, int Nn, int NB) {
    __shared__ int cnt_[MAXNB];
    __shared__ int cur_[MAXNB];
    const int t = threadIdx.x;
    const int e0 = blockIdx.x * 4096;
    for (int i = t; i < NB; i += 256) cnt_[i] = 0;
    __syncthreads();
    const int is64 = *flag;
    for (int k = 0; k < 16; k++) {
        int e = e0 + k * 256 + t;
        if (e < E) {
            int d = is64 ? (int)((const long long*)edges_raw)[(size_t)E + e]
                         : ((const int*)edges_raw)[(size_t)E + e];
            d = min(max(d, 0), Nn - 1);
            atomicAdd(&cnt_[d >> 6], 1);
        }
    }
    __syncthreads();
    for (int i = t; i < NB; i += 256) {
        int c = cnt_[i];
        cur_[i] = (c > 0) ? atomicAdd(&gCur[i], c) : 0;
    }
    __syncthreads();
    for (int k = 0; k < 16; k++) {
        int e = e0 + k * 256 + t;
        if (e < E) {
            int s, d;
            if (is64) {
                s = (int)((const long long*)edges_raw)[e];
                d = (int)((const long long*)edges_raw)[(size_t)E + e];
            } else {
                s = ((const int*)edges_raw)[e];
                d = ((const int*)edges_raw)[(size_t)E + e];
            }
            s = min(max(s, 0), Nn - 1);
            d = min(max(d, 0), Nn - 1);
            int b = d >> 6;
            int p = atomicAdd(&cur_[b], 1);
            if (p < CAPB)
                binned[(size_t)b * CAPB + p] = (unsigned)s | ((unsigned)(d & 63) << 23);
        }
    }
}

// ---------------------------------------------------------------------------
// pass B: per 64-node bucket, LDS CSR, gather-aggregate into AGG cols 0..255
// (sum 0..127, max 128..255; 0 for deg==0). x read from AGG cols 256..383.
// ---------------------------------------------------------------------------
__global__ __launch_bounds__(256) void k_bagg(const unsigned* __restrict__ binned,
                                              const int* __restrict__ gCur,
                                              const void* __restrict__ edges_raw,
                                              const int* __restrict__ flag,
                                              unsigned short* __restrict__ AGG,
                                              int E, int Nn) {
    __shared__ unsigned ent[CAPB];
    __shared__ unsigned lsrc[CAPB];
    __shared__ int deg_[64], off_[64], cur2_[64];
    __shared__ int sa[64], sb[64];
    const int t = threadIdx.x;
    const int wave = t >> 6;
    const int lane = t & 63;
    const int b = blockIdx.x;
    const int node0 = b << 6;
    const int nloc = min(64, Nn - node0);
    const int cnt = gCur[b];
    const int c2 = lane * 2;

    if (cnt <= CAPB) {
        for (int i = t; i < cnt; i += 256) ent[i] = binned[(size_t)b * CAPB + i];
        if (t < 64) deg_[t] = 0;
        __syncthreads();
        for (int i = t; i < cnt; i += 256) atomicAdd(&deg_[ent[i] >> 23], 1);
        __syncthreads();
        if (t < 64) sa[t] = deg_[t];
        __syncthreads();
        for (int off = 1; off < 64; off <<= 1) {
            if (t < 64) sb[t] = sa[t] + ((t >= off) ? sa[t - off] : 0);
            __syncthreads();
            if (t < 64) sa[t] = sb[t];
            __syncthreads();
        }
        if (t < 64) {
            off_[t] = sa[t] - deg_[t];
            cur2_[t] = off_[t];
        }
        __syncthreads();
        for (int i = t; i < cnt; i += 256) {
            unsigned e = ent[i];
            int dl = e >> 23;
            int p = atomicAdd(&cur2_[dl], 1);
            lsrc[p] = e & 0x7FFFFF;
        }
        __syncthreads();
        for (int ln = wave; ln < nloc; ln += 4) {
            const int o = off_[ln];
            const int d = deg_[ln];
            float sx = 0.f, sy = 0.f;
            float mx = -INFINITY, my = -INFINITY;
            int e = 0;
            for (; e + 1 < d; e += 2) {
                int s0 = lsrc[o + e];
                int s1 = lsrc[o + e + 1];
                unsigned v0 = *(const unsigned*)(AGG + (size_t)s0 * 384 + 256 + c2);
                unsigned v1 = *(const unsigned*)(AGG + (size_t)s1 * 384 + 256 + c2);
                float ax = bf2f((unsigned short)(v0 & 0xffff));
                float ay = bf2f((unsigned short)(v0 >> 16));
                float bx = bf2f((unsigned short)(v1 & 0xffff));
                float by = bf2f((unsigned short)(v1 >> 16));
                sx += ax + bx; sy += ay + by;
                mx = fmaxf(mx, fmaxf(ax, bx)); my = fmaxf(my, fmaxf(ay, by));
            }
            if (e < d) {
                int s0 = lsrc[o + e];
                unsigned v0 = *(const unsigned*)(AGG + (size_t)s0 * 384 + 256 + c2);
                float ax = bf2f((unsigned short)(v0 & 0xffff));
                float ay = bf2f((unsigned short)(v0 >> 16));
                sx += ax; sy += ay;
                mx = fmaxf(mx, ax); my = fmaxf(my, ay);
            }
            if (d == 0) { mx = 0.f; my = 0.f; }
            unsigned short* row = AGG + (size_t)(node0 + ln) * 384;
            *(unsigned*)(row + c2) = (unsigned)f2bf(sx) | ((unsigned)f2bf(sy) << 16);
            *(unsigned*)(row + 128 + c2) = (unsigned)f2bf(mx) | ((unsigned)f2bf(my) << 16);
        }
    } else {
        // overflow slow path (formal correctness; ~never taken)
        const int is64 = *flag;
        for (int ln = wave; ln < nloc; ln += 4) {
            const int node = node0 + ln;
            float sx = 0.f, sy = 0.f;
            float mx = -INFINITY, my = -INFINITY;
            int d = 0;
            for (int e = 0; e < E; e++) {
                int dd = is64 ? (int)((const long long*)edges_raw)[(size_t)E + e]
                              : ((const int*)edges_raw)[(size_t)E + e];
                dd = min(max(dd, 0), Nn - 1);
                if (dd == node) {
                    int s = is64 ? (int)((const long long*)edges_raw)[e]
                                 : ((const int*)edges_raw)[e];
                    s = min(max(s, 0), Nn - 1);
                    unsigned v0 = *(const unsigned*)(AGG + (size_t)s * 384 + 256 + c2);
                    float ax = bf2f((unsigned short)(v0 & 0xffff));
                    float ay = bf2f((unsigned short)(v0 >> 16));
                    sx += ax; sy += ay;
                    mx = fmaxf(mx, ax); my = fmaxf(my, ay);
                    d++;
                }
            }
            if (d == 0) { mx = 0.f; my = 0.f; }
            unsigned short* row = AGG + (size_t)node * 384;
            *(unsigned*)(row + c2) = (unsigned)f2bf(sx) | ((unsigned)f2bf(sy) << 16);
            *(unsigned*)(row + 128 + c2) = (unsigned)f2bf(mx) | ((unsigned)f2bf(my) << 16);
        }
    }
}

// ---------------------------------------------------------------------------
// bf16 MFMA GEMM, 128x128 tile, 4 waves, 4x4 of 16x16x32 MFMA.
// grid = dim3(ncolblocks, nrowblocks): blocks sharing an A row-panel are
// dispatch-adjacent -> panel read once into L2/LLC.
// Epilogue (GRUE=0): LDS-repacked bf16 stores, optional AFFINE/LEAKY/STATS.
// Epilogue (GRUE=1): gate columns are PERMUTED (see k_fusew) so nt = gate;
//   computes GRU per-lane in registers: h=(1-z)*tanh(i_n+r*h_n)+z*x and
//   writes h (N x 128 bf16) directly -> no Gb intermediate, no k_gru pass.
// ---------------------------------------------------------------------------
#define GP 40  // LDS row pitch (bf16): 80B, 16B-aligned, near-conflict-free

template <int AFFINE, int LEAKY, int STATS, int GRUE>
__global__ __launch_bounds__(256) void k_mgemm(
    const unsigned short* __restrict__ A, int lda,
    const unsigned short* __restrict__ Bt,
    const float* __restrict__ bias,
    const float* __restrict__ sumA, const float* __restrict__ sqA,
    const float* __restrict__ gA, const float* __restrict__ beA,
    unsigned short* __restrict__ Cb, int ldc,
    int M, int K, float* __restrict__ sumO, float* __restrict__ sqO, float invN,
    const unsigned short* __restrict__ Xb) {
    __shared__ unsigned short ABs[2 * 128 * GP];  // As | Bs; reused for repack
    __shared__ float sc1[256], sh1[256];
    __shared__ float ssum[128], ssq[128];
    unsigned short* As = ABs;
    unsigned short* Bs = ABs + 128 * GP;

    const int t = threadIdx.x;
    const int lane = t & 63;
    const int wave = t >> 6;
    const int wr = (wave >> 1) * 64;
    const int wc = (wave & 1) * 64;
    const int quad = lane >> 4;
    const int l16 = lane & 15;

    const int r0 = blockIdx.y * 128;
    const int j0 = blockIdx.x * 128;

    if (AFFINE) {
        float m = sumA[t] * invN;
        float v = sqA[t] * invN - m * m;
        if (v < 0.f) v = 0.f;
        float rs = rsqrtf(v + 1e-5f);
        float sc = gA[t] * rs;
        sc1[t] = sc;
        sh1[t] = beA[t] - m * sc;
    }
    if (STATS && t < 128) { ssum[t] = 0.f; ssq[t] = 0.f; }
    if (AFFINE || STATS) __syncthreads();

    f32x4 acc[4][4];
#pragma unroll
    for (int i = 0; i < 4; i++)
#pragma unroll
        for (int j = 0; j < 4; j++) acc[i][j] = (f32x4){0.f, 0.f, 0.f, 0.f};

    const int srow = t >> 2;
    const int sk = (t & 3) * 8;

    for (int k0 = 0; k0 < K; k0 += 32) {
        union U8 { float4 f; unsigned short u[8]; } uv;
#pragma unroll
        for (int p = 0; p < 2; p++) {
            int row = p * 64 + srow;
            int gr = r0 + row;
            float4 v = make_float4(0.f, 0.f, 0.f, 0.f);
            if (gr < M) v = *(const float4*)(A + (size_t)gr * lda + k0 + sk);
            if (AFFINE) {
                uv.f = v;
#pragma unroll
                for (int q = 0; q < 8; q++) {
                    float f = bf2f(uv.u[q]) * sc1[k0 + sk + q] + sh1[k0 + sk + q];
                    uv.u[q] = f2bf(f);
                }
                v = uv.f;
            }
            *(float4*)&As[row * GP + sk] = v;
        }
#pragma unroll
        for (int p = 0; p < 2; p++) {
            int row = p * 64 + srow;
            float4 v = *(const float4*)(Bt + (size_t)(j0 + row) * K + k0 + sk);
            *(float4*)&Bs[row * GP + sk] = v;
        }
        __syncthreads();
        bf16x8 af[4], bfr[4];
#pragma unroll
        for (int i = 0; i < 4; i++) {
            af[i] = *(bf16x8*)&As[(wr + i * 16 + l16) * GP + quad * 8];
            bfr[i] = *(bf16x8*)&Bs[(wc + i * 16 + l16) * GP + quad * 8];
        }
#pragma unroll
        for (int mt = 0; mt < 4; mt++)
#pragma unroll
            for (int nt = 0; nt < 4; nt++)
                acc[mt][nt] = __builtin_amdgcn_mfma_f32_16x16x32_bf16(
                    af[mt], bfr[nt], acc[mt][nt], 0, 0, 0);
        __syncthreads();
    }

    if (GRUE) {
        // ---- GRU epilogue: nt=gate (0:r 1:z 2:i_n 3:h_n), dim = dimb+l16 ----
        // C/D map: col = lane&15, row = quad*4+reg (within each 16x16)
        const int dimb = (j0 + wc) >> 2;       // global hidden-dim base for wave
        const int dloc = (wc >> 2) + l16;      // 0..31 block-local dim
        const float bR = bias[j0 + wc + l16];
        const float bZ = bias[j0 + wc + 16 + l16];
        const float bI = bias[j0 + wc + 32 + l16];
        const float bH = bias[j0 + wc + 48 + l16];
#pragma unroll
        for (int mt = 0; mt < 4; mt++) {
#pragma unroll
            for (int reg = 0; reg < 4; reg++) {
                int rloc = wr + mt * 16 + quad * 4 + reg;
                int grow = r0 + rloc;
                float r = 1.0f / (1.0f + expf(-(acc[mt][0][reg] + bR)));
                float z = 1.0f / (1.0f + expf(-(acc[mt][1][reg] + bZ)));
                float nn = tanhf(acc[mt][2][reg] + bI + r * (acc[mt][3][reg] + bH));
                float xv = 0.f;
                if (grow < M) xv = bf2f(Xb[(size_t)grow * 384 + 256 + dimb + l16]);
                float h = (1.0f - z) * nn + z * xv;
                ABs[rloc * 40 + dloc] = f2bf(h);
            }
        }
        __syncthreads();
        // coalesced 16B stores: 128 rows x 32 dims -> hb16[, j0/4 .. j0/4+32)
#pragma unroll
        for (int p = 0; p < 2; p++) {
            int id = p * 256 + t;              // 0..511 = 128 rows x 4 chunks
            int rloc = id >> 2, ck = id & 3;
            int grow = r0 + rloc;
            if (grow < M)
                *(float4*)(Cb + (size_t)grow * ldc + (j0 >> 2) + ck * 8) =
                    *(const float4*)&ABs[rloc * 40 + ck * 8];
        }
        return;
    }

    // ---- standard epilogue: repack via LDS, coalesced 16B stores ----
    // C/D map: col = lane&15, row = quad*4+reg (within each 16x16)
#pragma unroll
    for (int half = 0; half < 2; half++) {
        if (wr == half * 64) {
#pragma unroll
            for (int nt = 0; nt < 4; nt++) {
                int colLoc = wc + nt * 16 + l16;
                float bv = bias[j0 + colLoc];
                float s = 0.f, q = 0.f;
#pragma unroll
                for (int mt = 0; mt < 4; mt++) {
#pragma unroll
                    for (int reg = 0; reg < 4; reg++) {
                        int rloc = mt * 16 + quad * 4 + reg;
                        float v = acc[mt][nt][reg] + bv;
                        if (LEAKY) v = (v >= 0.f) ? v : 0.01f * v;
                        if (STATS && (r0 + half * 64 + rloc) < M) { s += v; q += v * v; }
                        ABs[rloc * 128 + colLoc] = f2bf(v);
                    }
                }
                if (STATS) {
                    atomicAdd(&ssum[colLoc], s);
                    atomicAdd(&ssq[colLoc], q);
                }
            }
        }
        __syncthreads();
#pragma unroll
        for (int p = 0; p < 4; p++) {
            int id = p * 256 + t;      // 0..1023 = 64 rows x 16 chunks
            int rloc = id >> 4;
            int ck = id & 15;
            int grow = r0 + half * 64 + rloc;
            if (grow < M)
                *(float4*)(Cb + (size_t)grow * ldc + j0 + ck * 8) =
                    *(const float4*)&ABs[rloc * 128 + ck * 8];
        }
        __syncthreads();
    }
    if (STATS && t < 128) {
        atomicAdd(&sumO[j0 + t], ssum[t]);
        atomicAdd(&sqO[j0 + t], ssq[t]);
    }
}

// out(fp32) = bf2f(ypre)*scale2 + shift2 (BN2 finalize inline)
__global__ void k_affine2(const unsigned short* __restrict__ ypre, float* __restrict__ out,
                          const float* __restrict__ sum2, const float* __restrict__ sq2,
                          const float* __restrict__ g2, const float* __restrict__ be2,
                          int total, float invN) {
    __shared__ float sc[128], sh[128];
    int t = threadIdx.x;
    if (t < 128) {
        float m = sum2[t] * invN;
        float v = sq2[t] * invN - m * m;
        if (v < 0.f) v = 0.f;
        float rs = rsqrtf(v + 1e-5f);
        float s = g2[t] * rs;
        sc[t] = s;
        sh[t] = be2[t] - m * s;
    }
    __syncthreads();
    int idx = blockIdx.x * 256 + t;
    if (idx >= total) return;
    int c = idx & 127;
    out[idx] = bf2f(ypre[idx]) * sc[c] + sh[c];
}

// ---------------------------------------------------------------------------
extern "C" void kernel_launch(void* const* d_in, const int* in_sizes, int n_in,
                              void* d_out, int out_size, void* d_ws, size_t ws_size,
                              hipStream_t stream) {
    const float* x       = (const float*)d_in[0];
    const void*  edges   = d_in[1];
    const float* W_merge = (const float*)d_in[2];
    const float* b_merge = (const float*)d_in[3];
    const float* W_ih    = (const float*)d_in[4];
    const float* W_hh    = (const float*)d_in[5];
    const float* b_ih    = (const float*)d_in[6];
    const float* b_hh    = (const float*)d_in[7];
    const float* W1      = (const float*)d_in[8];
    const float* b1      = (const float*)d_in[9];
    const float* g1      = (const float*)d_in[10];
    const float* be1     = (const float*)d_in[11];
    const float* W2      = (const float*)d_in[12];
    const float* b2      = (const float*)d_in[13];
    const float* g2      = (const float*)d_in[14];
    const float* be2     = (const float*)d_in[15];

    const int N = in_sizes[0] / DD;
    const int E = in_sizes[1] / 2;
    float* out = (float*)d_out;

    size_t need = ((size_t)640 * N + 120000) * sizeof(float);
    if (ws_size < need) {
        k_wsfail<<<(out_size + 255) / 256, 256, 0, stream>>>(
            out, (float)(ws_size >> 20), out_size);
        return;
    }

    const int NB = (N + 63) >> 6;   // 64-node buckets

    float* ws = (float*)d_ws;
    // [0,192N): AGG bf16 Nx384 (sum|max|x) -> later y1b bf16 Nx256 at [0,128N),
    //                                         ypre bf16 Nx128 at [128N,192N)
    // [448N,512N): h bf16 Nx128
    // [512N,...): binned (NB*CAPB uints) + gCur + weights + sums
    unsigned short* AGG  = (unsigned short*)ws;
    unsigned short* y1b  = (unsigned short*)ws;
    unsigned short* ypre = (unsigned short*)(ws + (size_t)128 * N);
    unsigned short* hb16 = (unsigned short*)(ws + (size_t)448 * N);

    unsigned* binned = (unsigned*)(ws + (size_t)512 * N);
    int* gCur = (int*)(binned + (size_t)NB * CAPB);

    float* wbase = (float*)(gCur + NB + 64);
    unsigned short* BtG = (unsigned short*)wbase;                 // 512*384 el
    unsigned short* w1T = (unsigned short*)(wbase + 98304);       // 32768 el
    unsigned short* w2T = (unsigned short*)(wbase + 98304 + 16384);
    float* biasG = wbase + 98304 + 32768;   // 512
    float* sums  = biasG + 512;             // 768
    float* sum1 = sums, *sq1 = sums + 256, *sum2 = sums + 512, *sq2 = sums + 640;
    int*   flag  = (int*)(sums + 768);

    const int nrb  = (N + 127) / 128;
    const int ncvt = (N * DD + 255) / 256;
    const float invN = 1.0f / (float)N;

    // 1. setup (detect, zeros, w1T/w2T, x->AGG)
    k_setup<<<264 + ncvt, 256, 0, stream>>>(
        (const int*)edges, flag, sums, gCur, NB, W1, W2, w1T, w2T, x, AGG, N * DD);
    // 2. fused gate weights, gate-permuted columns (fp32 dot, one bf16 rounding)
    k_fusew<<<512, 256, 0, stream>>>(W_merge, W_ih, W_hh, b_merge, b_ih, b_hh, BtG, biasG);
    // 3. bin edges
    k_bin<<<(E + 4095) / 4096, 256, 0, stream>>>(edges, flag, gCur, binned, E, N, NB);
    // 4. per-bucket aggregate -> AGG cols 0..255
    k_bagg<<<NB, 256, 0, stream>>>(binned, gCur, edges, flag, AGG, E, N);
    // 5. fused G2'+GRU: h = GRU(AGG @ BtG + biasG, x)  (K=384, F=512 -> 128)
    k_mgemm<0, 0, 0, 1><<<dim3(4, nrb), 256, 0, stream>>>(
        AGG, 384, BtG, biasG, nullptr, nullptr, nullptr, nullptr,
        hb16, 128, N, 384, nullptr, nullptr, invN, AGG);
    // 6. G4: y1b = leaky(h @ w1T + b1) + stats1  (K=128, F=256)
    k_mgemm<0, 1, 1, 0><<<dim3(2, nrb), 256, 0, stream>>>(
        hb16, 128, w1T, b1, nullptr, nullptr, nullptr, nullptr,
        y1b, 256, N, 128, sum1, sq1, invN, nullptr);
    // 7. G5: ypre = leaky(bn1(y1b) @ w2T + b2) + stats2  (K=256, F=128)
    k_mgemm<1, 1, 1, 0><<<dim3(1, nrb), 256, 0, stream>>>(
        y1b, 256, w2T, b2, sum1, sq1, g1, be1,
        ypre, 128, N, 256, sum2, sq2, invN, nullptr);
    // 8. BN2 finalize + affine -> fp32 out
    k_affine2<<<ncvt, 256, 0, stream>>>(ypre, out, sum2, sq2, g2, be2, N * DD, invN);
}

// Round 2
// 498.691 us; speedup vs baseline: 1.1375x; 1.0629x over previous
//
#include <hip/hip_runtime.h>
#include <math.h>

#define DD 128
#define CAPB 2048            // per-bucket capacity; mean ~1024 at E/N=16, 64-node buckets
#define MAXNB 1600           // max buckets (N <= 102400)

typedef __attribute__((ext_vector_type(8))) short bf16x8;
typedef __attribute__((ext_vector_type(4))) float f32x4;

__device__ __forceinline__ unsigned short f2bf(float f) {
    unsigned u = __float_as_uint(f);
    unsigned r = u + 0x7FFF + ((u >> 16) & 1);
    return (unsigned short)(r >> 16);
}
__device__ __forceinline__ float bf2f(unsigned short h) {
    return __uint_as_float(((unsigned)h) << 16);
}

// async global->LDS, 16B per lane; LDS dest = wave-uniform base + lane*16
__device__ __forceinline__ void gld16(const unsigned short* g, unsigned short* l) {
    __builtin_amdgcn_global_load_lds(
        (const __attribute__((address_space(1))) void*)g,
        (__attribute__((address_space(3))) void*)l, 16, 0, 0);
}

__global__ void k_wsfail(float* __restrict__ out, float val, int n) {
    int i = blockIdx.x * 256 + threadIdx.x;
    if (i < n) out[i] = (i == 0) ? val : 0.0f;
}

// ---------------------------------------------------------------------------
// k_setup: detect + zero sums/gCur + w1T/w2T transposes + x->AGG[,256:384)
// ---------------------------------------------------------------------------
__global__ void k_setup(const int* __restrict__ e32, int* __restrict__ flag,
                        float* __restrict__ sums, int* __restrict__ gCur, int NB,
                        const float* __restrict__ W1, const float* __restrict__ W2,
                        unsigned short* __restrict__ w1T, unsigned short* __restrict__ w2T,
                        const float* __restrict__ x, unsigned short* __restrict__ AGG,
                        int total_x) {
    const int bid = blockIdx.x;
    const int t = threadIdx.x;
    if (bid == 0) {
        if (t == 0) {
            int f = 1;
            for (int i = 1; i < 16; i += 2) f &= (e32[i] == 0);
            *flag = f;  // 1 => int64 edges
        }
        for (int i = t; i < 768; i += 256) sums[i] = 0.0f;
    } else if (bid < 8) {
        int i = (bid - 1) * 256 + t;
        if (i < NB) gCur[i] = 0;
    } else if (bid < 136) {
        int i = (bid - 8) * 256 + t;   // < 32768
        int j = i >> 7, k = i & 127;
        w1T[j * 128 + k] = f2bf(W1[k * 256 + j]);
    } else if (bid < 264) {
        int i = (bid - 136) * 256 + t; // < 32768
        int j = i >> 8, k = i & 255;
        w2T[j * 256 + k] = f2bf(W2[k * 128 + j]);
    } else {
        int idx = (bid - 264) * 256 + t;
        if (idx < total_x) {
            int i = idx >> 7, j = idx & 127;
            AGG[(size_t)i * 384 + 256 + j] = f2bf(x[idx]);
        }
    }
}

// ---------------------------------------------------------------------------
// k_fusew: fold merge-linear into gate weights (fp32 math, one bf16 rounding)
// Gate-permuted physical columns: pj(d,g) = (d>>4)*64 + g*16 + (d&15)
// ---------------------------------------------------------------------------
__global__ void k_fusew(const float* __restrict__ Wm, const float* __restrict__ Wih,
                        const float* __restrict__ Whh, const float* __restrict__ bm,
                        const float* __restrict__ b_ih, const float* __restrict__ b_hh,
                        unsigned short* __restrict__ BtG, float* __restrict__ biasG) {
    const int j = blockIdx.x;
    const int c = threadIdx.x;
    const int g = j >> 7, d = j & 127;
    const int pj = ((d >> 4) << 6) + (g << 4) + (d & 15);
    float acc = 0.0f;
    if (j < 384) {
        const float* wr = Wih + (size_t)j * 128;
        const float* wc = Wm + (size_t)c * 128;
        for (int m = 0; m < 128; m++) acc += wc[m] * wr[m];
    }
    BtG[(size_t)pj * 384 + c] = f2bf(acc);
    if (c < 128) {
        float v = 0.0f;
        if (j < 256) v = Whh[(size_t)j * 128 + c];
        else if (j >= 384) v = Whh[(size_t)(j - 128) * 128 + c];
        BtG[(size_t)pj * 384 + 256 + c] = f2bf(v);
    }
    if (c == 0) {
        float b;
        if (j < 256) b = b_ih[j] + b_hh[j];
        else if (j < 384) b = b_ih[j];
        else b = b_hh[j - 128];
        if (j < 384) {
            const float* wr = Wih + (size_t)j * 128;
            float dd = 0.0f;
            for (int m = 0; m < 128; m++) dd += bm[m] * wr[m];
            b += dd;
        }
        biasG[pj] = b;
    }
}

// ---------------------------------------------------------------------------
// pass A: bin edges into per-bucket windows (bucket = dst>>6, 64 nodes)
// ---------------------------------------------------------------------------
__global__ __launch_bounds__(256) void k_bin(const void* __restrict__ edges_raw,
                                             const int* __restrict__ flag,
                                             int* __restrict__ gCur,
                                             unsigned* __restrict__ binned,
                                             int E, int Nn, int NB) {
    __shared__ int cnt_[MAXNB];
    __shared__ int cur_[MAXNB];
    const int t = threadIdx.x;
    const int e0 = blockIdx.x * 4096;
    for (int i = t; i < NB; i += 256) cnt_[i] = 0;
    __syncthreads();
    const int is64 = *flag;
    for (int k = 0; k < 16; k++) {
        int e = e0 + k * 256 + t;
        if (e < E) {
            int d = is64 ? (int)((const long long*)edges_raw)[(size_t)E + e]
                         : ((const int*)edges_raw)[(size_t)E + e];
            d = min(max(d, 0), Nn - 1);
            atomicAdd(&cnt_[d >> 6], 1);
        }
    }
    __syncthreads();
    for (int i = t; i < NB; i += 256) {
        int c = cnt_[i];
        cur_[i] = (c > 0) ? atomicAdd(&gCur[i], c) : 0;
    }
    __syncthreads();
    for (int k = 0; k < 16; k++) {
        int e = e0 + k * 256 + t;
        if (e < E) {
            int s, d;
            if (is64) {
                s = (int)((const long long*)edges_raw)[e];
                d = (int)((const long long*)edges_raw)[(size_t)E + e];
            } else {
                s = ((const int*)edges_raw)[e];
                d = ((const int*)edges_raw)[(size_t)E + e];
            }
            s = min(max(s, 0), Nn - 1);
            d = min(max(d, 0), Nn - 1);
            int b = d >> 6;
            int p = atomicAdd(&cur_[b], 1);
            if (p < CAPB)
                binned[(size_t)b * CAPB + p] = (unsigned)s | ((unsigned)(d & 63) << 23);
        }
    }
}

// ---------------------------------------------------------------------------
// pass B: per 64-node bucket, LDS CSR, gather-aggregate into AGG cols 0..255
// ---------------------------------------------------------------------------
__global__ __launch_bounds__(256) void k_bagg(const unsigned* __restrict__ binned,
                                              const int* __restrict__ gCur,
                                              const void* __restrict__ edges_raw,
                                              const int* __restrict__ flag,
                                              unsigned short* __restrict__ AGG,
                                              int E, int Nn) {
    __shared__ unsigned ent[CAPB];
    __shared__ unsigned lsrc[CAPB];
    __shared__ int deg_[64], off_[64], cur2_[64];
    __shared__ int sa[64], sb[64];
    const int t = threadIdx.x;
    const int wave = t >> 6;
    const int lane = t & 63;
    const int b = blockIdx.x;
    const int node0 = b << 6;
    const int nloc = min(64, Nn - node0);
    const int cnt = gCur[b];
    const int c2 = lane * 2;

    if (cnt <= CAPB) {
        for (int i = t; i < cnt; i += 256) ent[i] = binned[(size_t)b * CAPB + i];
        if (t < 64) deg_[t] = 0;
        __syncthreads();
        for (int i = t; i < cnt; i += 256) atomicAdd(&deg_[ent[i] >> 23], 1);
        __syncthreads();
        if (t < 64) sa[t] = deg_[t];
        __syncthreads();
        for (int off = 1; off < 64; off <<= 1) {
            if (t < 64) sb[t] = sa[t] + ((t >= off) ? sa[t - off] : 0);
            __syncthreads();
            if (t < 64) sa[t] = sb[t];
            __syncthreads();
        }
        if (t < 64) {
            off_[t] = sa[t] - deg_[t];
            cur2_[t] = off_[t];
        }
        __syncthreads();
        for (int i = t; i < cnt; i += 256) {
            unsigned e = ent[i];
            int dl = e >> 23;
            int p = atomicAdd(&cur2_[dl], 1);
            lsrc[p] = e & 0x7FFFFF;
        }
        __syncthreads();
        for (int ln = wave; ln < nloc; ln += 4) {
            const int o = off_[ln];
            const int d = deg_[ln];
            float sx = 0.f, sy = 0.f;
            float mx = -INFINITY, my = -INFINITY;
            int e = 0;
            for (; e + 1 < d; e += 2) {
                int s0 = lsrc[o + e];
                int s1 = lsrc[o + e + 1];
                unsigned v0 = *(const unsigned*)(AGG + (size_t)s0 * 384 + 256 + c2);
                unsigned v1 = *(const unsigned*)(AGG + (size_t)s1 * 384 + 256 + c2);
                float ax = bf2f((unsigned short)(v0 & 0xffff));
                float ay = bf2f((unsigned short)(v0 >> 16));
                float bx = bf2f((unsigned short)(v1 & 0xffff));
                float by = bf2f((unsigned short)(v1 >> 16));
                sx += ax + bx; sy += ay + by;
                mx = fmaxf(mx, fmaxf(ax, bx)); my = fmaxf(my, fmaxf(ay, by));
            }
            if (e < d) {
                int s0 = lsrc[o + e];
                unsigned v0 = *(const unsigned*)(AGG + (size_t)s0 * 384 + 256 + c2);
                float ax = bf2f((unsigned short)(v0 & 0xffff));
                float ay = bf2f((unsigned short)(v0 >> 16));
                sx += ax; sy += ay;
                mx = fmaxf(mx, ax); my = fmaxf(my, ay);
            }
            if (d == 0) { mx = 0.f; my = 0.f; }
            unsigned short* row = AGG + (size_t)(node0 + ln) * 384;
            *(unsigned*)(row + c2) = (unsigned)f2bf(sx) | ((unsigned)f2bf(sy) << 16);
            *(unsigned*)(row + 128 + c2) = (unsigned)f2bf(mx) | ((unsigned)f2bf(my) << 16);
        }
    } else {
        // overflow slow path (formal correctness; ~never taken)
        const int is64 = *flag;
        for (int ln = wave; ln < nloc; ln += 4) {
            const int node = node0 + ln;
            float sx = 0.f, sy = 0.f;
            float mx = -INFINITY, my = -INFINITY;
            int d = 0;
            for (int e = 0; e < E; e++) {
                int dd = is64 ? (int)((const long long*)edges_raw)[(size_t)E + e]
                              : ((const int*)edges_raw)[(size_t)E + e];
                dd = min(max(dd, 0), Nn - 1);
                if (dd == node) {
                    int s = is64 ? (int)((const long long*)edges_raw)[e]
                                 : ((const int*)edges_raw)[e];
                    s = min(max(s, 0), Nn - 1);
                    unsigned v0 = *(const unsigned*)(AGG + (size_t)s * 384 + 256 + c2);
                    float ax = bf2f((unsigned short)(v0 & 0xffff));
                    float ay = bf2f((unsigned short)(v0 >> 16));
                    sx += ax; sy += ay;
                    mx = fmaxf(mx, ax); my = fmaxf(my, ay);
                    d++;
                }
            }
            if (d == 0) { mx = 0.f; my = 0.f; }
            unsigned short* row = AGG + (size_t)node * 384;
            *(unsigned*)(row + c2) = (unsigned)f2bf(sx) | ((unsigned)f2bf(sy) << 16);
            *(unsigned*)(row + 128 + c2) = (unsigned)f2bf(mx) | ((unsigned)f2bf(my) << 16);
        }
    }
}

// ---------------------------------------------------------------------------
// bf16 MFMA GEMM, 128x128 tile, 4 waves, 4x4 of 16x16x32 MFMA.
// - global_load_lds (16B) staging into linear [128][32] LDS, granule XOR
//   swizzle sig = (row>>1)&3 applied to the GLOBAL source address and the
//   fragment read (both-sides, rule #21). AFFINE keeps reg-staging for A
//   (BN1 transform), load-early/write-late.
// - Stage-ahead double buffer: issue tile k+1 before computing tile k;
//   one barrier per iter, so the vmcnt drain lands after compute.
// - XCD-grouped remap (bijective): the column-siblings of one A row-panel
//   run on the same XCD -> panel L2 hits instead of HBM refetch.
// Epilogues unchanged (GRUE gate-permuted GRU / LEAKY+STATS standard).
// ---------------------------------------------------------------------------
template <int AFFINE, int LEAKY, int STATS, int GRUE>
__global__ __launch_bounds__(256) void k_mgemm(
    const unsigned short* __restrict__ A, int lda,
    const unsigned short* __restrict__ Bt,
    const float* __restrict__ bias,
    const float* __restrict__ sumA, const float* __restrict__ sqA,
    const float* __restrict__ gA, const float* __restrict__ beA,
    unsigned short* __restrict__ Cb, int ldc,
    int M, int K, float* __restrict__ sumO, float* __restrict__ sqO, float invN,
    const unsigned short* __restrict__ Xb) {
    __shared__ unsigned short ABs[2][2][4096];  // [buf][A|B][128*32]
    __shared__ float sc1[256], sh1[256];
    __shared__ float ssum[128], ssq[128];
    unsigned short* RP = &ABs[0][0][0];         // epilogue repack region

    const int t = threadIdx.x;
    const int lane = t & 63;
    const int wave = t >> 6;
    const int wr = (wave >> 1) * 64;
    const int wc = (wave & 1) * 64;
    const int quad = lane >> 4;
    const int l16 = lane & 15;
    const int sig = (l16 >> 1) & 3;             // fragment-read swizzle

    // XCD-grouped bijective remap (m204): consecutive per-XCD ids walk
    // column-fastest, so a row-panel's siblings share an XCD/L2.
    const int ncb = gridDim.x;
    const int nwg = ncb * gridDim.y;
    {
    }
    int lin = blockIdx.y * ncb + blockIdx.x;
    const int qq = nwg >> 3, rr = nwg & 7;
    const int xcd = lin & 7, pos = lin >> 3;
    const int nl = (xcd < rr ? xcd * (qq + 1) : rr * (qq + 1) + (xcd - rr) * qq) + pos;
    const int j0 = (nl % ncb) * 128;
    const int r0 = (nl / ncb) * 128;

    if (AFFINE) {
        float m = sumA[t] * invN;
        float v = sqA[t] * invN - m * m;
        if (v < 0.f) v = 0.f;
        float rs = rsqrtf(v + 1e-5f);
        float sc = gA[t] * rs;
        sc1[t] = sc;
        sh1[t] = beA[t] - m * sc;
    }
    if (STATS && t < 128) { ssum[t] = 0.f; ssq[t] = 0.f; }
    if (AFFINE || STATS) __syncthreads();

    f32x4 acc[4][4];
#pragma unroll
    for (int i = 0; i < 4; i++)
#pragma unroll
        for (int j = 0; j < 4; j++) acc[i][j] = (f32x4){0.f, 0.f, 0.f, 0.f};

    // staging geometry: call (wave,p) covers granules [(2w+p)*64, +64)
    // lane l -> row = (2w+p)*16 + (l>>2), phys granule l&3,
    // source granule gsw = (l&3) ^ ((l>>3)&3)  [= phys ^ ((row>>1)&3)]
    const int rowl = lane >> 2;
    const int gsw8 = (((lane & 3) ^ ((lane >> 3) & 3))) * 8;

    // AFFINE reg-staging geometry (writes same swizzled layout)
    const int srow = t >> 2;
    const int sg8 = (t & 3) * 8;
    const int swz8 = (((t & 3) ^ ((t >> 3) & 3))) * 8;
    float4 areg[2];

    auto stageA = [&](int buf, int k0) {
#pragma unroll
        for (int p = 0; p < 2; p++) {
            int row = (wave * 2 + p) * 16 + rowl;
            int gr = r0 + row;
            if (gr >= M) gr = M - 1;
            gld16(A + (size_t)gr * lda + k0 + gsw8,
                  &ABs[buf][0][(wave * 2 + p) * 512]);
        }
    };
    auto stageB = [&](int buf, int k0) {
#pragma unroll
        for (int p = 0; p < 2; p++) {
            int row = (wave * 2 + p) * 16 + rowl;
            gld16(Bt + (size_t)(j0 + row) * K + k0 + gsw8,
                  &ABs[buf][1][(wave * 2 + p) * 512]);
        }
    };
    auto loadA = [&](int k0) {
#pragma unroll
        for (int p = 0; p < 2; p++) {
            int gr = r0 + p * 64 + srow;
            areg[p] = make_float4(0.f, 0.f, 0.f, 0.f);
            if (gr < M) areg[p] = *(const float4*)(A + (size_t)gr * lda + k0 + sg8);
        }
    };
    auto writeA = [&](int buf, int k0) {
        union U8 { float4 f; unsigned short u[8]; } uv;
#pragma unroll
        for (int p = 0; p < 2; p++) {
            uv.f = areg[p];
#pragma unroll
            for (int q = 0; q < 8; q++) {
                float f = bf2f(uv.u[q]) * sc1[k0 + sg8 + q] + sh1[k0 + sg8 + q];
                uv.u[q] = f2bf(f);
            }
            *(float4*)&ABs[buf][0][(p * 64 + srow) * 32 + swz8] = uv.f;
        }
    };

    // prologue: stage tile 0 into buf 0
    if (AFFINE) { loadA(0); writeA(0, 0); } else stageA(0, 0);
    stageB(0, 0);
    __syncthreads();

    int buf = 0;
    for (int k0 = 0; k0 < K; k0 += 32) {
        const int kn = k0 + 32;
        const bool hasNext = kn < K;
        if (hasNext) {
            if (AFFINE) loadA(kn); else stageA(buf ^ 1, kn);
            stageB(buf ^ 1, kn);
        }
        bf16x8 af[4], bfr[4];
#pragma unroll
        for (int i = 0; i < 4; i++) {
            af[i]  = *(bf16x8*)&ABs[buf][0][(wr + i * 16 + l16) * 32 + (quad ^ sig) * 8];
            bfr[i] = *(bf16x8*)&ABs[buf][1][(wc + i * 16 + l16) * 32 + (quad ^ sig) * 8];
        }
#pragma unroll
        for (int mt = 0; mt < 4; mt++)
#pragma unroll
            for (int nt = 0; nt < 4; nt++)
                acc[mt][nt] = __builtin_amdgcn_mfma_f32_16x16x32_bf16(
                    af[mt], bfr[nt], acc[mt][nt], 0, 0, 0);
        if (AFFINE && hasNext) writeA(buf ^ 1, kn);
        __syncthreads();
        buf ^= 1;
    }

    if (GRUE) {
        // ---- GRU epilogue: nt=gate (0:r 1:z 2:i_n 3:h_n), dim = dimb+l16 ----
        const int dimb = (j0 + wc) >> 2;       // global hidden-dim base for wave
        const int dloc = (wc >> 2) + l16;      // 0..31 block-local dim
        const float bR = bias[j0 + wc + l16];
        const float bZ = bias[j0 + wc + 16 + l16];
        const float bI = bias[j0 + wc + 32 + l16];
        const float bH = bias[j0 + wc + 48 + l16];
#pragma unroll
        for (int mt = 0; mt < 4; mt++) {
#pragma unroll
            for (int reg = 0; reg < 4; reg++) {
                int rloc = wr + mt * 16 + quad * 4 + reg;
                int grow = r0 + rloc;
                float r = 1.0f / (1.0f + expf(-(acc[mt][0][reg] + bR)));
                float z = 1.0f / (1.0f + expf(-(acc[mt][1][reg] + bZ)));
                float nn = tanhf(acc[mt][2][reg] + bI + r * (acc[mt][3][reg] + bH));
                float xv = 0.f;
                if (grow < M) xv = bf2f(Xb[(size_t)grow * 384 + 256 + dimb + l16]);
                float h = (1.0f - z) * nn + z * xv;
                RP[rloc * 40 + dloc] = f2bf(h);
            }
        }
        __syncthreads();
#pragma unroll
        for (int p = 0; p < 2; p++) {
            int id = p * 256 + t;              // 0..511 = 128 rows x 4 chunks
            int rloc = id >> 2, ck = id & 3;
            int grow = r0 + rloc;
            if (grow < M)
                *(float4*)(Cb + (size_t)grow * ldc + (j0 >> 2) + ck * 8) =
                    *(const float4*)&RP[rloc * 40 + ck * 8];
        }
        return;
    }

    // ---- standard epilogue: repack via LDS, coalesced 16B stores ----
#pragma unroll
    for (int half = 0; half < 2; half++) {
        if (wr == half * 64) {
#pragma unroll
            for (int nt = 0; nt < 4; nt++) {
                int colLoc = wc + nt * 16 + l16;
                float bv = bias[j0 + colLoc];
                float s = 0.f, q = 0.f;
#pragma unroll
                for (int mt = 0; mt < 4; mt++) {
#pragma unroll
                    for (int reg = 0; reg < 4; reg++) {
                        int rloc = mt * 16 + quad * 4 + reg;
                        float v = acc[mt][nt][reg] + bv;
                        if (LEAKY) v = (v >= 0.f) ? v : 0.01f * v;
                        if (STATS && (r0 + half * 64 + rloc) < M) { s += v; q += v * v; }
                        RP[rloc * 128 + colLoc] = f2bf(v);
                    }
                }
                if (STATS) {
                    atomicAdd(&ssum[colLoc], s);
                    atomicAdd(&ssq[colLoc], q);
                }
            }
        }
        __syncthreads();
#pragma unroll
        for (int p = 0; p < 4; p++) {
            int id = p * 256 + t;      // 0..1023 = 64 rows x 16 chunks
            int rloc = id >> 4;
            int ck = id & 15;
            int grow = r0 + half * 64 + rloc;
            if (grow < M)
                *(float4*)(Cb + (size_t)grow * ldc + j0 + ck * 8) =
                    *(const float4*)&RP[rloc * 128 + ck * 8];
        }
        __syncthreads();
    }
    if (STATS && t < 128) {
        atomicAdd(&sumO[j0 + t], ssum[t]);
        atomicAdd(&sqO[j0 + t], ssq[t]);
    }
}

// out(fp32) = bf2f(ypre)*scale2 + shift2 (BN2 finalize inline)
__global__ void k_affine2(const unsigned short* __restrict__ ypre, float* __restrict__ out,
                          const float* __restrict__ sum2, const float* __restrict__ sq2,
                          const float* __restrict__ g2, const float* __restrict__ be2,
                          int total, float invN) {
    __shared__ float sc[128], sh[128];
    int t = threadIdx.x;
    if (t < 128) {
        float m = sum2[t] * invN;
        float v = sq2[t] * invN - m * m;
        if (v < 0.f) v = 0.f;
        float rs = rsqrtf(v + 1e-5f);
        float s = g2[t] * rs;
        sc[t] = s;
        sh[t] = be2[t] - m * s;
    }
    __syncthreads();
    int idx = blockIdx.x * 256 + t;
    if (idx >= total) return;
    int c = idx & 127;
    out[idx] = bf2f(ypre[idx]) * sc[c] + sh[c];
}

// ---------------------------------------------------------------------------
extern "C" void kernel_launch(void* const* d_in, const int* in_sizes, int n_in,
                              void* d_out, int out_size, void* d_ws, size_t ws_size,
                              hipStream_t stream) {
    const float* x       = (const float*)d_in[0];
    const void*  edges   = d_in[1];
    const float* W_merge = (const float*)d_in[2];
    const float* b_merge = (const float*)d_in[3];
    const float* W_ih    = (const float*)d_in[4];
    const float* W_hh    = (const float*)d_in[5];
    const float* b_ih    = (const float*)d_in[6];
    const float* b_hh    = (const float*)d_in[7];
    const float* W1      = (const float*)d_in[8];
    const float* b1      = (const float*)d_in[9];
    const float* g1      = (const float*)d_in[10];
    const float* be1     = (const float*)d_in[11];
    const float* W2      = (const float*)d_in[12];
    const float* b2      = (const float*)d_in[13];
    const float* g2      = (const float*)d_in[14];
    const float* be2     = (const float*)d_in[15];

    const int N = in_sizes[0] / DD;
    const int E = in_sizes[1] / 2;
    float* out = (float*)d_out;

    size_t need = ((size_t)640 * N + 120000) * sizeof(float);
    if (ws_size < need) {
        k_wsfail<<<(out_size + 255) / 256, 256, 0, stream>>>(
            out, (float)(ws_size >> 20), out_size);
        return;
    }

    const int NB = (N + 63) >> 6;   // 64-node buckets

    float* ws = (float*)d_ws;
    // [0,192N): AGG bf16 Nx384 (sum|max|x) -> later y1b bf16 Nx256 at [0,128N),
    //                                         ypre bf16 Nx128 at [128N,192N)
    // [448N,512N): h bf16 Nx128
    // [512N,...): binned (NB*CAPB uints) + gCur + weights + sums
    unsigned short* AGG  = (unsigned short*)ws;
    unsigned short* y1b  = (unsigned short*)ws;
    unsigned short* ypre = (unsigned short*)(ws + (size_t)128 * N);
    unsigned short* hb16 = (unsigned short*)(ws + (size_t)448 * N);

    unsigned* binned = (unsigned*)(ws + (size_t)512 * N);
    int* gCur = (int*)(binned + (size_t)NB * CAPB);

    float* wbase = (float*)(gCur + NB + 64);
    unsigned short* BtG = (unsigned short*)wbase;                 // 512*384 el
    unsigned short* w1T = (unsigned short*)(wbase + 98304);       // 32768 el
    unsigned short* w2T = (unsigned short*)(wbase + 98304 + 16384);
    float* biasG = wbase + 98304 + 32768;   // 512
    float* sums  = biasG + 512;             // 768
    float* sum1 = sums, *sq1 = sums + 256, *sum2 = sums + 512, *sq2 = sums + 640;
    int*   flag  = (int*)(sums + 768);

    const int nrb  = (N + 127) / 128;
    const int ncvt = (N * DD + 255) / 256;
    const float invN = 1.0f / (float)N;

    // 1. setup (detect, zeros, w1T/w2T, x->AGG)
    k_setup<<<264 + ncvt, 256, 0, stream>>>(
        (const int*)edges, flag, sums, gCur, NB, W1, W2, w1T, w2T, x, AGG, N * DD);
    // 2. fused gate weights, gate-permuted columns (fp32 dot, one bf16 rounding)
    k_fusew<<<512, 256, 0, stream>>>(W_merge, W_ih, W_hh, b_merge, b_ih, b_hh, BtG, biasG);
    // 3. bin edges
    k_bin<<<(E + 4095) / 4096, 256, 0, stream>>>(edges, flag, gCur, binned, E, N, NB);
    // 4. per-bucket aggregate -> AGG cols 0..255
    k_bagg<<<NB, 256, 0, stream>>>(binned, gCur, edges, flag, AGG, E, N);
    // 5. fused G2'+GRU: h = GRU(AGG @ BtG + biasG, x)  (K=384, F=512 -> 128)
    k_mgemm<0, 0, 0, 1><<<dim3(4, nrb), 256, 0, stream>>>(
        AGG, 384, BtG, biasG, nullptr, nullptr, nullptr, nullptr,
        hb16, 128, N, 384, nullptr, nullptr, invN, AGG);
    // 6. G4: y1b = leaky(h @ w1T + b1) + stats1  (K=128, F=256)
    k_mgemm<0, 1, 1, 0><<<dim3(2, nrb), 256, 0, stream>>>(
        hb16, 128, w1T, b1, nullptr, nullptr, nullptr, nullptr,
        y1b, 256, N, 128, sum1, sq1, invN, nullptr);
    // 7. G5: ypre = leaky(bn1(y1b) @ w2T + b2) + stats2  (K=256, F=128)
    k_mgemm<1, 1, 1, 0><<<dim3(1, nrb), 256, 0, stream>>>(
        y1b, 256, w2T, b2, sum1, sq1, g1, be1,
        ypre, 128, N, 256, sum2, sq2, invN, nullptr);
    // 8. BN2 finalize + affine -> fp32 out
    k_affine2<<<ncvt, 256, 0, stream>>>(ypre, out, sum2, sq2, g2, be2, N * DD, invN);
}

// Round 3
// 459.099 us; speedup vs baseline: 1.2356x; 1.0862x over previous
//
#include <hip/hip_runtime.h>
#include <math.h>

#define DD 128
#define CAPB 2048            // per-bucket capacity; mean ~1024 at E/N=16, 64-node buckets
#define MAXNB 1600           // max buckets (N <= 102400)

typedef __attribute__((ext_vector_type(8))) short bf16x8;
typedef __attribute__((ext_vector_type(4))) float f32x4;

__device__ __forceinline__ unsigned short f2bf(float f) {
    unsigned u = __float_as_uint(f);
    unsigned r = u + 0x7FFF + ((u >> 16) & 1);
    return (unsigned short)(r >> 16);
}
__device__ __forceinline__ float bf2f(unsigned short h) {
    return __uint_as_float(((unsigned)h) << 16);
}

// fast sigmoid/tanh: v_exp_f32 + v_rcp_f32 (~1e-6 rel err, saturates correctly)
__device__ __forceinline__ float fsigm(float x) {
    float e = __builtin_amdgcn_exp2f(-1.442695041f * x);
    return __builtin_amdgcn_rcpf(1.0f + e);
}
__device__ __forceinline__ float ftanh(float x) {
    float e = __builtin_amdgcn_exp2f(2.885390082f * x);   // exp(2x)
    return 1.0f - 2.0f * __builtin_amdgcn_rcpf(1.0f + e);
}

// async global->LDS, 16B per lane; LDS dest = wave-uniform base + lane*16
__device__ __forceinline__ void gld16(const unsigned short* g, unsigned short* l) {
    __builtin_amdgcn_global_load_lds(
        (const __attribute__((address_space(1))) void*)g,
        (__attribute__((address_space(3))) void*)l, 16, 0, 0);
}

__global__ void k_wsfail(float* __restrict__ out, float val, int n) {
    int i = blockIdx.x * 256 + threadIdx.x;
    if (i < n) out[i] = (i == 0) ? val : 0.0f;
}

// ---------------------------------------------------------------------------
// k_setup: detect + zero sums/gCur + w1T/w2T transposes + x->AGG[,256:384)
// cvtx blocks handle 4 elems/thread (float4 load, 8B store)
// ---------------------------------------------------------------------------
__global__ void k_setup(const int* __restrict__ e32, int* __restrict__ flag,
                        float* __restrict__ sums, int* __restrict__ gCur, int NB,
                        const float* __restrict__ W1, const float* __restrict__ W2,
                        unsigned short* __restrict__ w1T, unsigned short* __restrict__ w2T,
                        const float* __restrict__ x, unsigned short* __restrict__ AGG,
                        int total_x4) {
    const int bid = blockIdx.x;
    const int t = threadIdx.x;
    if (bid == 0) {
        if (t == 0) {
            int f = 1;
            for (int i = 1; i < 16; i += 2) f &= (e32[i] == 0);
            *flag = f;  // 1 => int64 edges
        }
        for (int i = t; i < 768; i += 256) sums[i] = 0.0f;
    } else if (bid < 8) {
        int i = (bid - 1) * 256 + t;
        if (i < NB) gCur[i] = 0;
    } else if (bid < 136) {
        int i = (bid - 8) * 256 + t;   // < 32768
        int j = i >> 7, k = i & 127;
        w1T[j * 128 + k] = f2bf(W1[k * 256 + j]);
    } else if (bid < 264) {
        int i = (bid - 136) * 256 + t; // < 32768
        int j = i >> 8, k = i & 255;
        w2T[j * 256 + k] = f2bf(W2[k * 128 + j]);
    } else {
        int idx = (bid - 264) * 256 + t;
        if (idx < total_x4) {
            int i = idx >> 5, j4 = (idx & 31) * 4;
            float4 v = *(const float4*)(x + (size_t)i * 128 + j4);
            unsigned lo = (unsigned)f2bf(v.x) | ((unsigned)f2bf(v.y) << 16);
            unsigned hi = (unsigned)f2bf(v.z) | ((unsigned)f2bf(v.w) << 16);
            unsigned short* p = AGG + (size_t)i * 384 + 256 + j4;
            *(unsigned*)(p) = lo;
            *(unsigned*)(p + 2) = hi;
        }
    }
}

// ---------------------------------------------------------------------------
// k_fusew: fold merge-linear into gate weights (fp32 math, one bf16 rounding)
// Gate-permuted physical columns: pj(d,g) = (d>>4)*64 + g*16 + (d&15)
// ---------------------------------------------------------------------------
__global__ void k_fusew(const float* __restrict__ Wm, const float* __restrict__ Wih,
                        const float* __restrict__ Whh, const float* __restrict__ bm,
                        const float* __restrict__ b_ih, const float* __restrict__ b_hh,
                        unsigned short* __restrict__ BtG, float* __restrict__ biasG) {
    const int j = blockIdx.x;
    const int c = threadIdx.x;
    const int g = j >> 7, d = j & 127;
    const int pj = ((d >> 4) << 6) + (g << 4) + (d & 15);
    float acc = 0.0f;
    if (j < 384) {
        const float* wr = Wih + (size_t)j * 128;
        const float* wc = Wm + (size_t)c * 128;
        for (int m = 0; m < 128; m++) acc += wc[m] * wr[m];
    }
    BtG[(size_t)pj * 384 + c] = f2bf(acc);
    if (c < 128) {
        float v = 0.0f;
        if (j < 256) v = Whh[(size_t)j * 128 + c];
        else if (j >= 384) v = Whh[(size_t)(j - 128) * 128 + c];
        BtG[(size_t)pj * 384 + 256 + c] = f2bf(v);
    }
    if (c == 0) {
        float b;
        if (j < 256) b = b_ih[j] + b_hh[j];
        else if (j < 384) b = b_ih[j];
        else b = b_hh[j - 128];
        if (j < 384) {
            const float* wr = Wih + (size_t)j * 128;
            float dd = 0.0f;
            for (int m = 0; m < 128; m++) dd += bm[m] * wr[m];
            b += dd;
        }
        biasG[pj] = b;
    }
}

// ---------------------------------------------------------------------------
// pass A: bin edges into per-bucket windows (bucket = dst>>6, 64 nodes)
// ---------------------------------------------------------------------------
__global__ __launch_bounds__(256) void k_bin(const void* __restrict__ edges_raw,
                                             const int* __restrict__ flag,
                                             int* __restrict__ gCur,
                                             unsigned* __restrict__ binned,
                                             int E, int Nn, int NB) {
    __shared__ int cnt_[MAXNB];
    __shared__ int cur_[MAXNB];
    const int t = threadIdx.x;
    const int e0 = blockIdx.x * 4096;
    for (int i = t; i < NB; i += 256) cnt_[i] = 0;
    __syncthreads();
    const int is64 = *flag;
    for (int k = 0; k < 16; k++) {
        int e = e0 + k * 256 + t;
        if (e < E) {
            int d = is64 ? (int)((const long long*)edges_raw)[(size_t)E + e]
                         : ((const int*)edges_raw)[(size_t)E + e];
            d = min(max(d, 0), Nn - 1);
            atomicAdd(&cnt_[d >> 6], 1);
        }
    }
    __syncthreads();
    for (int i = t; i < NB; i += 256) {
        int c = cnt_[i];
        cur_[i] = (c > 0) ? atomicAdd(&gCur[i], c) : 0;
    }
    __syncthreads();
    for (int k = 0; k < 16; k++) {
        int e = e0 + k * 256 + t;
        if (e < E) {
            int s, d;
            if (is64) {
                s = (int)((const long long*)edges_raw)[e];
                d = (int)((const long long*)edges_raw)[(size_t)E + e];
            } else {
                s = ((const int*)edges_raw)[e];
                d = ((const int*)edges_raw)[(size_t)E + e];
            }
            s = min(max(s, 0), Nn - 1);
            d = min(max(d, 0), Nn - 1);
            int b = d >> 6;
            int p = atomicAdd(&cur_[b], 1);
            if (p < CAPB)
                binned[(size_t)b * CAPB + p] = (unsigned)s | ((unsigned)(d & 63) << 23);
        }
    }
}

// ---------------------------------------------------------------------------
// pass B: per 64-node bucket, LDS CSR, gather-aggregate into AGG cols 0..255
// inner gather 4-unrolled for memory-level parallelism
// ---------------------------------------------------------------------------
__global__ __launch_bounds__(256) void k_bagg(const unsigned* __restrict__ binned,
                                              const int* __restrict__ gCur,
                                              const void* __restrict__ edges_raw,
                                              const int* __restrict__ flag,
                                              unsigned short* __restrict__ AGG,
                                              int E, int Nn) {
    __shared__ unsigned ent[CAPB];
    __shared__ unsigned lsrc[CAPB];
    __shared__ int deg_[64], off_[64], cur2_[64];
    __shared__ int sa[64], sb[64];
    const int t = threadIdx.x;
    const int wave = t >> 6;
    const int lane = t & 63;
    const int b = blockIdx.x;
    const int node0 = b << 6;
    const int nloc = min(64, Nn - node0);
    const int cnt = gCur[b];
    const int c2 = lane * 2;

    if (cnt <= CAPB) {
        for (int i = t; i < cnt; i += 256) ent[i] = binned[(size_t)b * CAPB + i];
        if (t < 64) deg_[t] = 0;
        __syncthreads();
        for (int i = t; i < cnt; i += 256) atomicAdd(&deg_[ent[i] >> 23], 1);
        __syncthreads();
        if (t < 64) sa[t] = deg_[t];
        __syncthreads();
        for (int off = 1; off < 64; off <<= 1) {
            if (t < 64) sb[t] = sa[t] + ((t >= off) ? sa[t - off] : 0);
            __syncthreads();
            if (t < 64) sa[t] = sb[t];
            __syncthreads();
        }
        if (t < 64) {
            off_[t] = sa[t] - deg_[t];
            cur2_[t] = off_[t];
        }
        __syncthreads();
        for (int i = t; i < cnt; i += 256) {
            unsigned e = ent[i];
            int dl = e >> 23;
            int p = atomicAdd(&cur2_[dl], 1);
            lsrc[p] = e & 0x7FFFFF;
        }
        __syncthreads();
        for (int ln = wave; ln < nloc; ln += 4) {
            const int o = off_[ln];
            const int d = deg_[ln];
            float sx = 0.f, sy = 0.f;
            float mx = -INFINITY, my = -INFINITY;
            int e = 0;
            for (; e + 3 < d; e += 4) {
                int s0 = lsrc[o + e], s1 = lsrc[o + e + 1];
                int s2 = lsrc[o + e + 2], s3 = lsrc[o + e + 3];
                unsigned v0 = *(const unsigned*)(AGG + (size_t)s0 * 384 + 256 + c2);
                unsigned v1 = *(const unsigned*)(AGG + (size_t)s1 * 384 + 256 + c2);
                unsigned v2 = *(const unsigned*)(AGG + (size_t)s2 * 384 + 256 + c2);
                unsigned v3 = *(const unsigned*)(AGG + (size_t)s3 * 384 + 256 + c2);
                float a0 = bf2f((unsigned short)(v0 & 0xffff)), a1 = bf2f((unsigned short)(v0 >> 16));
                float b0 = bf2f((unsigned short)(v1 & 0xffff)), b1 = bf2f((unsigned short)(v1 >> 16));
                float c0 = bf2f((unsigned short)(v2 & 0xffff)), c1 = bf2f((unsigned short)(v2 >> 16));
                float d0 = bf2f((unsigned short)(v3 & 0xffff)), d1 = bf2f((unsigned short)(v3 >> 16));
                sx += (a0 + b0) + (c0 + d0); sy += (a1 + b1) + (c1 + d1);
                mx = fmaxf(fmaxf(mx, fmaxf(a0, b0)), fmaxf(c0, d0));
                my = fmaxf(fmaxf(my, fmaxf(a1, b1)), fmaxf(c1, d1));
            }
            for (; e < d; e++) {
                int s0 = lsrc[o + e];
                unsigned v0 = *(const unsigned*)(AGG + (size_t)s0 * 384 + 256 + c2);
                float ax = bf2f((unsigned short)(v0 & 0xffff));
                float ay = bf2f((unsigned short)(v0 >> 16));
                sx += ax; sy += ay;
                mx = fmaxf(mx, ax); my = fmaxf(my, ay);
            }
            if (d == 0) { mx = 0.f; my = 0.f; }
            unsigned short* row = AGG + (size_t)(node0 + ln) * 384;
            *(unsigned*)(row + c2) = (unsigned)f2bf(sx) | ((unsigned)f2bf(sy) << 16);
            *(unsigned*)(row + 128 + c2) = (unsigned)f2bf(mx) | ((unsigned)f2bf(my) << 16);
        }
    } else {
        // overflow slow path (formal correctness; ~never taken)
        const int is64 = *flag;
        for (int ln = wave; ln < nloc; ln += 4) {
            const int node = node0 + ln;
            float sx = 0.f, sy = 0.f;
            float mx = -INFINITY, my = -INFINITY;
            int d = 0;
            for (int e = 0; e < E; e++) {
                int dd = is64 ? (int)((const long long*)edges_raw)[(size_t)E + e]
                              : ((const int*)edges_raw)[(size_t)E + e];
                dd = min(max(dd, 0), Nn - 1);
                if (dd == node) {
                    int s = is64 ? (int)((const long long*)edges_raw)[e]
                                 : ((const int*)edges_raw)[e];
                    s = min(max(s, 0), Nn - 1);
                    unsigned v0 = *(const unsigned*)(AGG + (size_t)s * 384 + 256 + c2);
                    float ax = bf2f((unsigned short)(v0 & 0xffff));
                    float ay = bf2f((unsigned short)(v0 >> 16));
                    sx += ax; sy += ay;
                    mx = fmaxf(mx, ax); my = fmaxf(my, ay);
                    d++;
                }
            }
            if (d == 0) { mx = 0.f; my = 0.f; }
            unsigned short* row = AGG + (size_t)node * 384;
            *(unsigned*)(row + c2) = (unsigned)f2bf(sx) | ((unsigned)f2bf(sy) << 16);
            *(unsigned*)(row + 128 + c2) = (unsigned)f2bf(mx) | ((unsigned)f2bf(my) << 16);
        }
    }
}

// ---------------------------------------------------------------------------
// bf16 MFMA GEMM, 128x128 tile, 4 waves, 4x4 of 16x16x32 MFMA.
// Non-AFFINE path: counted-vmcnt pipeline (T4) — raw s_barrier, 2-deep
//   stage-ahead via global_load_lds; next tile's 4 loads stay in flight
//   across the barrier (never vmcnt(0) mid-loop).
// AFFINE path: reg-staged A (BN1 transform) + __syncthreads (proven).
// GRU epilogue uses fast exp2/rcp sigmoid+tanh.
// ---------------------------------------------------------------------------
template <int AFFINE, int LEAKY, int STATS, int GRUE>
__global__ __launch_bounds__(256) void k_mgemm(
    const unsigned short* __restrict__ A, int lda,
    const unsigned short* __restrict__ Bt,
    const float* __restrict__ bias,
    const float* __restrict__ sumA, const float* __restrict__ sqA,
    const float* __restrict__ gA, const float* __restrict__ beA,
    unsigned short* __restrict__ Cb, int ldc,
    int M, int K, float* __restrict__ sumO, float* __restrict__ sqO, float invN,
    const unsigned short* __restrict__ Xb) {
    __shared__ unsigned short ABs[2][2][4096];  // [buf][A|B][128*32]
    __shared__ float sc1[256], sh1[256];
    __shared__ float ssum[128], ssq[128];
    unsigned short* RP = &ABs[0][0][0];         // epilogue repack region

    const int t = threadIdx.x;
    const int lane = t & 63;
    const int wave = t >> 6;
    const int wr = (wave >> 1) * 64;
    const int wc = (wave & 1) * 64;
    const int quad = lane >> 4;
    const int l16 = lane & 15;
    const int sig = (l16 >> 1) & 3;             // fragment-read swizzle

    // XCD-grouped bijective remap (m204)
    const int ncb = gridDim.x;
    const int nwg = ncb * gridDim.y;
    int lin = blockIdx.y * ncb + blockIdx.x;
    const int qq = nwg >> 3, rr = nwg & 7;
    const int xcd = lin & 7, pos = lin >> 3;
    const int nl = (xcd < rr ? xcd * (qq + 1) : rr * (qq + 1) + (xcd - rr) * qq) + pos;
    const int j0 = (nl % ncb) * 128;
    const int r0 = (nl / ncb) * 128;

    if (AFFINE) {
        float m = sumA[t] * invN;
        float v = sqA[t] * invN - m * m;
        if (v < 0.f) v = 0.f;
        float rs = rsqrtf(v + 1e-5f);
        float sc = gA[t] * rs;
        sc1[t] = sc;
        sh1[t] = beA[t] - m * sc;
    }
    if (STATS && t < 128) { ssum[t] = 0.f; ssq[t] = 0.f; }
    if (AFFINE || STATS) __syncthreads();

    f32x4 acc[4][4];
#pragma unroll
    for (int i = 0; i < 4; i++)
#pragma unroll
        for (int j = 0; j < 4; j++) acc[i][j] = (f32x4){0.f, 0.f, 0.f, 0.f};

    // staging geometry: call (wave,p) covers rows [(2w+p)*16, +16)
    const int rowl = lane >> 2;
    const int gsw8 = (((lane & 3) ^ ((lane >> 3) & 3))) * 8;

    // AFFINE reg-staging geometry (writes same swizzled layout)
    const int srow = t >> 2;
    const int sg8 = (t & 3) * 8;
    const int swz8 = (((t & 3) ^ ((t >> 3) & 3))) * 8;
    float4 areg[2];

    auto stageA = [&](int buf, int k0) {
#pragma unroll
        for (int p = 0; p < 2; p++) {
            int row = (wave * 2 + p) * 16 + rowl;
            int gr = r0 + row;
            if (gr >= M) gr = M - 1;
            gld16(A + (size_t)gr * lda + k0 + gsw8,
                  &ABs[buf][0][(wave * 2 + p) * 512]);
        }
    };
    auto stageB = [&](int buf, int k0) {
#pragma unroll
        for (int p = 0; p < 2; p++) {
            int row = (wave * 2 + p) * 16 + rowl;
            gld16(Bt + (size_t)(j0 + row) * K + k0 + gsw8,
                  &ABs[buf][1][(wave * 2 + p) * 512]);
        }
    };
    auto loadA = [&](int k0) {
#pragma unroll
        for (int p = 0; p < 2; p++) {
            int gr = r0 + p * 64 + srow;
            areg[p] = make_float4(0.f, 0.f, 0.f, 0.f);
            if (gr < M) areg[p] = *(const float4*)(A + (size_t)gr * lda + k0 + sg8);
        }
    };
    auto writeA = [&](int buf, int k0) {
        union U8 { float4 f; unsigned short u[8]; } uv;
#pragma unroll
        for (int p = 0; p < 2; p++) {
            uv.f = areg[p];
#pragma unroll
            for (int q = 0; q < 8; q++) {
                float f = bf2f(uv.u[q]) * sc1[k0 + sg8 + q] + sh1[k0 + sg8 + q];
                uv.u[q] = f2bf(f);
            }
            *(float4*)&ABs[buf][0][(p * 64 + srow) * 32 + swz8] = uv.f;
        }
    };

    if (!AFFINE) {
        // ---- counted-vmcnt pipeline: 2 tiles staged ahead, never drain to 0 ----
        stageA(0, 0); stageB(0, 0);
        if (32 < K) { stageA(1, 32); stageB(1, 32); }
        for (int k0 = 0; k0 < K; k0 += 32) {
            const int cur = (k0 >> 5) & 1;
            if (k0 + 32 < K)
                asm volatile("s_waitcnt vmcnt(4)\n\ts_barrier" ::: "memory");
            else
                asm volatile("s_waitcnt vmcnt(0)\n\ts_barrier" ::: "memory");
            bf16x8 af[4], bfr[4];
#pragma unroll
            for (int i = 0; i < 4; i++) {
                af[i]  = *(bf16x8*)&ABs[cur][0][(wr + i * 16 + l16) * 32 + (quad ^ sig) * 8];
                bfr[i] = *(bf16x8*)&ABs[cur][1][(wc + i * 16 + l16) * 32 + (quad ^ sig) * 8];
            }
            asm volatile("s_waitcnt lgkmcnt(0)\n\ts_barrier" ::: "memory");
            if (k0 + 64 < K) { stageA(cur, k0 + 64); stageB(cur, k0 + 64); }
#pragma unroll
            for (int mt = 0; mt < 4; mt++)
#pragma unroll
                for (int nt = 0; nt < 4; nt++)
                    acc[mt][nt] = __builtin_amdgcn_mfma_f32_16x16x32_bf16(
                        af[mt], bfr[nt], acc[mt][nt], 0, 0, 0);
        }
    } else {
        // ---- AFFINE: reg-staged A + __syncthreads double-buffer (proven) ----
        loadA(0); writeA(0, 0);
        stageB(0, 0);
        __syncthreads();
        int buf = 0;
        for (int k0 = 0; k0 < K; k0 += 32) {
            const int kn = k0 + 32;
            const bool hasNext = kn < K;
            if (hasNext) {
                loadA(kn);
                stageB(buf ^ 1, kn);
            }
            bf16x8 af[4], bfr[4];
#pragma unroll
            for (int i = 0; i < 4; i++) {
                af[i]  = *(bf16x8*)&ABs[buf][0][(wr + i * 16 + l16) * 32 + (quad ^ sig) * 8];
                bfr[i] = *(bf16x8*)&ABs[buf][1][(wc + i * 16 + l16) * 32 + (quad ^ sig) * 8];
            }
#pragma unroll
            for (int mt = 0; mt < 4; mt++)
#pragma unroll
                for (int nt = 0; nt < 4; nt++)
                    acc[mt][nt] = __builtin_amdgcn_mfma_f32_16x16x32_bf16(
                        af[mt], bfr[nt], acc[mt][nt], 0, 0, 0);
            if (hasNext) writeA(buf ^ 1, kn);
            __syncthreads();
            buf ^= 1;
        }
    }

    if (GRUE) {
        // ---- GRU epilogue: nt=gate (0:r 1:z 2:i_n 3:h_n), dim = dimb+l16 ----
        const int dimb = (j0 + wc) >> 2;       // global hidden-dim base for wave
        const int dloc = (wc >> 2) + l16;      // 0..31 block-local dim
        const float bR = bias[j0 + wc + l16];
        const float bZ = bias[j0 + wc + 16 + l16];
        const float bI = bias[j0 + wc + 32 + l16];
        const float bH = bias[j0 + wc + 48 + l16];
#pragma unroll
        for (int mt = 0; mt < 4; mt++) {
#pragma unroll
            for (int reg = 0; reg < 4; reg++) {
                int rloc = wr + mt * 16 + quad * 4 + reg;
                int grow = r0 + rloc;
                int gi = grow < M ? grow : M - 1;
                float r = fsigm(acc[mt][0][reg] + bR);
                float z = fsigm(acc[mt][1][reg] + bZ);
                float nn = ftanh(acc[mt][2][reg] + bI + r * (acc[mt][3][reg] + bH));
                float xv = bf2f(Xb[(size_t)gi * 384 + 256 + dimb + l16]);
                float h = (1.0f - z) * nn + z * xv;
                RP[rloc * 40 + dloc] = f2bf(h);
            }
        }
        __syncthreads();
#pragma unroll
        for (int p = 0; p < 2; p++) {
            int id = p * 256 + t;              // 0..511 = 128 rows x 4 chunks
            int rloc = id >> 2, ck = id & 3;
            int grow = r0 + rloc;
            if (grow < M)
                *(float4*)(Cb + (size_t)grow * ldc + (j0 >> 2) + ck * 8) =
                    *(const float4*)&RP[rloc * 40 + ck * 8];
        }
        return;
    }

    // ---- standard epilogue: repack via LDS, coalesced 16B stores ----
#pragma unroll
    for (int half = 0; half < 2; half++) {
        if (wr == half * 64) {
#pragma unroll
            for (int nt = 0; nt < 4; nt++) {
                int colLoc = wc + nt * 16 + l16;
                float bv = bias[j0 + colLoc];
                float s = 0.f, q = 0.f;
#pragma unroll
                for (int mt = 0; mt < 4; mt++) {
#pragma unroll
                    for (int reg = 0; reg < 4; reg++) {
                        int rloc = mt * 16 + quad * 4 + reg;
                        float v = acc[mt][nt][reg] + bv;
                        if (LEAKY) v = (v >= 0.f) ? v : 0.01f * v;
                        if (STATS && (r0 + half * 64 + rloc) < M) { s += v; q += v * v; }
                        RP[rloc * 128 + colLoc] = f2bf(v);
                    }
                }
                if (STATS) {
                    atomicAdd(&ssum[colLoc], s);
                    atomicAdd(&ssq[colLoc], q);
                }
            }
        }
        __syncthreads();
#pragma unroll
        for (int p = 0; p < 4; p++) {
            int id = p * 256 + t;      // 0..1023 = 64 rows x 16 chunks
            int rloc = id >> 4;
            int ck = id & 15;
            int grow = r0 + half * 64 + rloc;
            if (grow < M)
                *(float4*)(Cb + (size_t)grow * ldc + j0 + ck * 8) =
                    *(const float4*)&RP[rloc * 128 + ck * 8];
        }
        __syncthreads();
    }
    if (STATS && t < 128) {
        atomicAdd(&sumO[j0 + t], ssum[t]);
        atomicAdd(&sqO[j0 + t], ssq[t]);
    }
}

// out(fp32) = bf2f(ypre)*scale2 + shift2 (BN2 finalize inline)
__global__ void k_affine2(const unsigned short* __restrict__ ypre, float* __restrict__ out,
                          const float* __restrict__ sum2, const float* __restrict__ sq2,
                          const float* __restrict__ g2, const float* __restrict__ be2,
                          int total, float invN) {
    __shared__ float sc[128], sh[128];
    int t = threadIdx.x;
    if (t < 128) {
        float m = sum2[t] * invN;
        float v = sq2[t] * invN - m * m;
        if (v < 0.f) v = 0.f;
        float rs = rsqrtf(v + 1e-5f);
        float s = g2[t] * rs;
        sc[t] = s;
        sh[t] = be2[t] - m * s;
    }
    __syncthreads();
    int idx = blockIdx.x * 256 + t;
    if (idx >= total) return;
    int c = idx & 127;
    out[idx] = bf2f(ypre[idx]) * sc[c] + sh[c];
}

// ---------------------------------------------------------------------------
extern "C" void kernel_launch(void* const* d_in, const int* in_sizes, int n_in,
                              void* d_out, int out_size, void* d_ws, size_t ws_size,
                              hipStream_t stream) {
    const float* x       = (const float*)d_in[0];
    const void*  edges   = d_in[1];
    const float* W_merge = (const float*)d_in[2];
    const float* b_merge = (const float*)d_in[3];
    const float* W_ih    = (const float*)d_in[4];
    const float* W_hh    = (const float*)d_in[5];
    const float* b_ih    = (const float*)d_in[6];
    const float* b_hh    = (const float*)d_in[7];
    const float* W1      = (const float*)d_in[8];
    const float* b1      = (const float*)d_in[9];
    const float* g1      = (const float*)d_in[10];
    const float* be1     = (const float*)d_in[11];
    const float* W2      = (const float*)d_in[12];
    const float* b2      = (const float*)d_in[13];
    const float* g2      = (const float*)d_in[14];
    const float* be2     = (const float*)d_in[15];

    const int N = in_sizes[0] / DD;
    const int E = in_sizes[1] / 2;
    float* out = (float*)d_out;

    size_t need = ((size_t)640 * N + 120000) * sizeof(float);
    if (ws_size < need) {
        k_wsfail<<<(out_size + 255) / 256, 256, 0, stream>>>(
            out, (float)(ws_size >> 20), out_size);
        return;
    }

    const int NB = (N + 63) >> 6;   // 64-node buckets

    float* ws = (float*)d_ws;
    // [0,192N): AGG bf16 Nx384 (sum|max|x) -> later y1b bf16 Nx256 at [0,128N),
    //                                         ypre bf16 Nx128 at [128N,192N)
    // [448N,512N): h bf16 Nx128
    // [512N,...): binned (NB*CAPB uints) + gCur + weights + sums
    unsigned short* AGG  = (unsigned short*)ws;
    unsigned short* y1b  = (unsigned short*)ws;
    unsigned short* ypre = (unsigned short*)(ws + (size_t)128 * N);
    unsigned short* hb16 = (unsigned short*)(ws + (size_t)448 * N);

    unsigned* binned = (unsigned*)(ws + (size_t)512 * N);
    int* gCur = (int*)(binned + (size_t)NB * CAPB);

    float* wbase = (float*)(gCur + NB + 64);
    unsigned short* BtG = (unsigned short*)wbase;                 // 512*384 el
    unsigned short* w1T = (unsigned short*)(wbase + 98304);       // 32768 el
    unsigned short* w2T = (unsigned short*)(wbase + 98304 + 16384);
    float* biasG = wbase + 98304 + 32768;   // 512
    float* sums  = biasG + 512;             // 768
    float* sum1 = sums, *sq1 = sums + 256, *sum2 = sums + 512, *sq2 = sums + 640;
    int*   flag  = (int*)(sums + 768);

    const int nrb  = (N + 127) / 128;
    const int ncvt = (N * DD + 255) / 256;
    const int ncvt4 = (N * 32 + 255) / 256;
    const float invN = 1.0f / (float)N;

    // 1. setup (detect, zeros, w1T/w2T, x->AGG)
    k_setup<<<264 + ncvt4, 256, 0, stream>>>(
        (const int*)edges, flag, sums, gCur, NB, W1, W2, w1T, w2T, x, AGG, N * 32);
    // 2. fused gate weights, gate-permuted columns (fp32 dot, one bf16 rounding)
    k_fusew<<<512, 256, 0, stream>>>(W_merge, W_ih, W_hh, b_merge, b_ih, b_hh, BtG, biasG);
    // 3. bin edges
    k_bin<<<(E + 4095) / 4096, 256, 0, stream>>>(edges, flag, gCur, binned, E, N, NB);
    // 4. per-bucket aggregate -> AGG cols 0..255
    k_bagg<<<NB, 256, 0, stream>>>(binned, gCur, edges, flag, AGG, E, N);
    // 5. fused G2'+GRU: h = GRU(AGG @ BtG + biasG, x)  (K=384, F=512 -> 128)
    k_mgemm<0, 0, 0, 1><<<dim3(4, nrb), 256, 0, stream>>>(
        AGG, 384, BtG, biasG, nullptr, nullptr, nullptr, nullptr,
        hb16, 128, N, 384, nullptr, nullptr, invN, AGG);
    // 6. G4: y1b = leaky(h @ w1T + b1) + stats1  (K=128, F=256)
    k_mgemm<0, 1, 1, 0><<<dim3(2, nrb), 256, 0, stream>>>(
        hb16, 128, w1T, b1, nullptr, nullptr, nullptr, nullptr,
        y1b, 256, N, 128, sum1, sq1, invN, nullptr);
    // 7. G5: ypre = leaky(bn1(y1b) @ w2T + b2) + stats2  (K=256, F=128)
    k_mgemm<1, 1, 1, 0><<<dim3(1, nrb), 256, 0, stream>>>(
        y1b, 256, w2T, b2, sum1, sq1, g1, be1,
        ypre, 128, N, 256, sum2, sq2, invN, nullptr);
    // 8. BN2 finalize + affine -> fp32 out
    k_affine2<<<ncvt, 256, 0, stream>>>(ypre, out, sum2, sq2, g2, be2, N * DD, invN);
}

// Round 4
// 445.202 us; speedup vs baseline: 1.2741x; 1.0312x over previous
//
#include <hip/hip_runtime.h>
#include <math.h>

#define DD 128
#define CAPB 2048            // per-bucket capacity; mean ~1024 at E/N=16, 64-node buckets
#define MAXNB 1600           // max buckets (N <= 102400)

typedef __attribute__((ext_vector_type(8))) short bf16x8;
typedef __attribute__((ext_vector_type(4))) float f32x4;

__device__ __forceinline__ unsigned short f2bf(float f) {
    unsigned u = __float_as_uint(f);
    unsigned r = u + 0x7FFF + ((u >> 16) & 1);
    return (unsigned short)(r >> 16);
}
__device__ __forceinline__ float bf2f(unsigned short h) {
    return __uint_as_float(((unsigned)h) << 16);
}

// fast sigmoid/tanh: v_exp_f32 + v_rcp_f32 (~1e-6 rel err, saturates correctly)
__device__ __forceinline__ float fsigm(float x) {
    float e = __builtin_amdgcn_exp2f(-1.442695041f * x);
    return __builtin_amdgcn_rcpf(1.0f + e);
}
__device__ __forceinline__ float ftanh(float x) {
    float e = __builtin_amdgcn_exp2f(2.885390082f * x);   // exp(2x)
    return 1.0f - 2.0f * __builtin_amdgcn_rcpf(1.0f + e);
}

// async global->LDS, 16B per lane; LDS dest = wave-uniform base + lane*16
__device__ __forceinline__ void gld16(const unsigned short* g, unsigned short* l) {
    __builtin_amdgcn_global_load_lds(
        (const __attribute__((address_space(1))) void*)g,
        (__attribute__((address_space(3))) void*)l, 16, 0, 0);
}

__global__ void k_wsfail(float* __restrict__ out, float val, int n) {
    int i = blockIdx.x * 256 + threadIdx.x;
    if (i < n) out[i] = (i == 0) ? val : 0.0f;
}

// ---------------------------------------------------------------------------
// k_setup: detect + zero sums/gCur + w1T/w2T transposes + x->AGG[,256:384)
// cvtx blocks handle 4 elems/thread (float4 load, 8B store)
// ---------------------------------------------------------------------------
__global__ void k_setup(const int* __restrict__ e32, int* __restrict__ flag,
                        float* __restrict__ sums, int* __restrict__ gCur, int NB,
                        const float* __restrict__ W1, const float* __restrict__ W2,
                        unsigned short* __restrict__ w1T, unsigned short* __restrict__ w2T,
                        const float* __restrict__ x, unsigned short* __restrict__ AGG,
                        int total_x4) {
    const int bid = blockIdx.x;
    const int t = threadIdx.x;
    if (bid == 0) {
        if (t == 0) {
            int f = 1;
            for (int i = 1; i < 16; i += 2) f &= (e32[i] == 0);
            *flag = f;  // 1 => int64 edges
        }
        for (int i = t; i < 768; i += 256) sums[i] = 0.0f;
    } else if (bid < 8) {
        int i = (bid - 1) * 256 + t;
        if (i < NB) gCur[i] = 0;
    } else if (bid < 136) {
        int i = (bid - 8) * 256 + t;   // < 32768
        int j = i >> 7, k = i & 127;
        w1T[j * 128 + k] = f2bf(W1[k * 256 + j]);
    } else if (bid < 264) {
        int i = (bid - 136) * 256 + t; // < 32768
        int j = i >> 8, k = i & 255;
        w2T[j * 256 + k] = f2bf(W2[k * 128 + j]);
    } else {
        int idx = (bid - 264) * 256 + t;
        if (idx < total_x4) {
            int i = idx >> 5, j4 = (idx & 31) * 4;
            float4 v = *(const float4*)(x + (size_t)i * 128 + j4);
            unsigned lo = (unsigned)f2bf(v.x) | ((unsigned)f2bf(v.y) << 16);
            unsigned hi = (unsigned)f2bf(v.z) | ((unsigned)f2bf(v.w) << 16);
            unsigned short* p = AGG + (size_t)i * 384 + 256 + j4;
            *(unsigned*)(p) = lo;
            *(unsigned*)(p + 2) = hi;
        }
    }
}

// ---------------------------------------------------------------------------
// k_fusew: fold merge-linear into gate weights (fp32 math, one bf16 rounding)
// Gate-permuted physical columns: pj(d,g) = (d>>4)*64 + g*16 + (d&15)
// ---------------------------------------------------------------------------
__global__ void k_fusew(const float* __restrict__ Wm, const float* __restrict__ Wih,
                        const float* __restrict__ Whh, const float* __restrict__ bm,
                        const float* __restrict__ b_ih, const float* __restrict__ b_hh,
                        unsigned short* __restrict__ BtG, float* __restrict__ biasG) {
    const int j = blockIdx.x;
    const int c = threadIdx.x;
    const int g = j >> 7, d = j & 127;
    const int pj = ((d >> 4) << 6) + (g << 4) + (d & 15);
    float acc = 0.0f;
    if (j < 384) {
        const float* wr = Wih + (size_t)j * 128;
        const float* wc = Wm + (size_t)c * 128;
        for (int m = 0; m < 128; m++) acc += wc[m] * wr[m];
    }
    BtG[(size_t)pj * 384 + c] = f2bf(acc);
    if (c < 128) {
        float v = 0.0f;
        if (j < 256) v = Whh[(size_t)j * 128 + c];
        else if (j >= 384) v = Whh[(size_t)(j - 128) * 128 + c];
        BtG[(size_t)pj * 384 + 256 + c] = f2bf(v);
    }
    if (c == 0) {
        float b;
        if (j < 256) b = b_ih[j] + b_hh[j];
        else if (j < 384) b = b_ih[j];
        else b = b_hh[j - 128];
        if (j < 384) {
            const float* wr = Wih + (size_t)j * 128;
            float dd = 0.0f;
            for (int m = 0; m < 128; m++) dd += bm[m] * wr[m];
            b += dd;
        }
        biasG[pj] = b;
    }
}

// ---------------------------------------------------------------------------
// pass A: bin edges into per-bucket windows (bucket = dst>>6, 64 nodes)
// ---------------------------------------------------------------------------
__global__ __launch_bounds__(256) void k_bin(const void* __restrict__ edges_raw,
                                             const int* __restrict__ flag,
                                             int* __restrict__ gCur,
                                             unsigned* __restrict__ binned,
                                             int E, int Nn, int NB) {
    __shared__ int cnt_[MAXNB];
    __shared__ int cur_[MAXNB];
    const int t = threadIdx.x;
    const int e0 = blockIdx.x * 4096;
    for (int i = t; i < NB; i += 256) cnt_[i] = 0;
    __syncthreads();
    const int is64 = *flag;
    for (int k = 0; k < 16; k++) {
        int e = e0 + k * 256 + t;
        if (e < E) {
            int d = is64 ? (int)((const long long*)edges_raw)[(size_t)E + e]
                         : ((const int*)edges_raw)[(size_t)E + e];
            d = min(max(d, 0), Nn - 1);
            atomicAdd(&cnt_[d >> 6], 1);
        }
    }
    __syncthreads();
    for (int i = t; i < NB; i += 256) {
        int c = cnt_[i];
        cur_[i] = (c > 0) ? atomicAdd(&gCur[i], c) : 0;
    }
    __syncthreads();
    for (int k = 0; k < 16; k++) {
        int e = e0 + k * 256 + t;
        if (e < E) {
            int s, d;
            if (is64) {
                s = (int)((const long long*)edges_raw)[e];
                d = (int)((const long long*)edges_raw)[(size_t)E + e];
            } else {
                s = ((const int*)edges_raw)[e];
                d = ((const int*)edges_raw)[(size_t)E + e];
            }
            s = min(max(s, 0), Nn - 1);
            d = min(max(d, 0), Nn - 1);
            int b = d >> 6;
            int p = atomicAdd(&cur_[b], 1);
            if (p < CAPB)
                binned[(size_t)b * CAPB + p] = (unsigned)s | ((unsigned)(d & 63) << 23);
        }
    }
}

// ---------------------------------------------------------------------------
// pass B: per 64-node bucket, LDS CSR, gather-aggregate into AGG cols 0..255
// - no ent[] staging buffer (binned read twice from global; L2-hot 2nd pass)
//   -> LDS ~9.4 KB, occupancy grid-limited instead of LDS-limited
// - lsrc holds pre-multiplied BYTE offsets (src*768+512): no per-edge mul
// - 8-wide unrolled gather for memory-level parallelism
// ---------------------------------------------------------------------------
__global__ __launch_bounds__(256) void k_bagg(const unsigned* __restrict__ binned,
                                              const int* __restrict__ gCur,
                                              const void* __restrict__ edges_raw,
                                              const int* __restrict__ flag,
                                              unsigned short* __restrict__ AGG,
                                              int E, int Nn) {
    __shared__ unsigned lsrc[CAPB];
    __shared__ int deg_[64], off_[64], cur2_[64];
    __shared__ int sa[64], sb[64];
    const int t = threadIdx.x;
    const int wave = t >> 6;
    const int lane = t & 63;
    const int b = blockIdx.x;
    const int node0 = b << 6;
    const int nloc = min(64, Nn - node0);
    const int cnt = gCur[b];
    const int c2 = lane * 2;            // ushort offset within row (write)
    const unsigned c4 = (unsigned)lane * 4u;  // byte offset within x-row (read)

    if (cnt <= CAPB) {
        if (t < 64) deg_[t] = 0;
        __syncthreads();
        for (int i = t; i < cnt; i += 256)
            atomicAdd(&deg_[binned[(size_t)b * CAPB + i] >> 23], 1);
        __syncthreads();
        if (t < 64) sa[t] = deg_[t];
        __syncthreads();
        for (int off = 1; off < 64; off <<= 1) {
            if (t < 64) sb[t] = sa[t] + ((t >= off) ? sa[t - off] : 0);
            __syncthreads();
            if (t < 64) sa[t] = sb[t];
            __syncthreads();
        }
        if (t < 64) {
            off_[t] = sa[t] - deg_[t];
            cur2_[t] = off_[t];
        }
        __syncthreads();
        for (int i = t; i < cnt; i += 256) {
            unsigned e = binned[(size_t)b * CAPB + i];
            int dl = e >> 23;
            int p = atomicAdd(&cur2_[dl], 1);
            lsrc[p] = (e & 0x7FFFFF) * 768u + 512u;   // byte offset of x-row
        }
        __syncthreads();
        const char* AGGb = (const char*)AGG;
        for (int ln = wave; ln < nloc; ln += 4) {
            const int o = off_[ln];
            const int d = deg_[ln];
            float sx = 0.f, sy = 0.f;
            float mx = -INFINITY, my = -INFINITY;
            int e = 0;
            for (; e + 7 < d; e += 8) {
                unsigned v[8];
#pragma unroll
                for (int u = 0; u < 8; u++)
                    v[u] = *(const unsigned*)(AGGb + lsrc[o + e + u] + c4);
#pragma unroll
                for (int u = 0; u < 8; u++) {
                    float lo = bf2f((unsigned short)(v[u] & 0xffff));
                    float hi = bf2f((unsigned short)(v[u] >> 16));
                    sx += lo; sy += hi;
                    mx = fmaxf(mx, lo); my = fmaxf(my, hi);
                }
            }
            for (; e + 3 < d; e += 4) {
                unsigned v[4];
#pragma unroll
                for (int u = 0; u < 4; u++)
                    v[u] = *(const unsigned*)(AGGb + lsrc[o + e + u] + c4);
#pragma unroll
                for (int u = 0; u < 4; u++) {
                    float lo = bf2f((unsigned short)(v[u] & 0xffff));
                    float hi = bf2f((unsigned short)(v[u] >> 16));
                    sx += lo; sy += hi;
                    mx = fmaxf(mx, lo); my = fmaxf(my, hi);
                }
            }
            for (; e < d; e++) {
                unsigned v0 = *(const unsigned*)(AGGb + lsrc[o + e] + c4);
                float lo = bf2f((unsigned short)(v0 & 0xffff));
                float hi = bf2f((unsigned short)(v0 >> 16));
                sx += lo; sy += hi;
                mx = fmaxf(mx, lo); my = fmaxf(my, hi);
            }
            if (d == 0) { mx = 0.f; my = 0.f; }
            unsigned short* row = AGG + (size_t)(node0 + ln) * 384;
            *(unsigned*)(row + c2) = (unsigned)f2bf(sx) | ((unsigned)f2bf(sy) << 16);
            *(unsigned*)(row + 128 + c2) = (unsigned)f2bf(mx) | ((unsigned)f2bf(my) << 16);
        }
    } else {
        // overflow slow path (formal correctness; ~never taken)
        const int is64 = *flag;
        for (int ln = wave; ln < nloc; ln += 4) {
            const int node = node0 + ln;
            float sx = 0.f, sy = 0.f;
            float mx = -INFINITY, my = -INFINITY;
            int d = 0;
            for (int e = 0; e < E; e++) {
                int dd = is64 ? (int)((const long long*)edges_raw)[(size_t)E + e]
                              : ((const int*)edges_raw)[(size_t)E + e];
                dd = min(max(dd, 0), Nn - 1);
                if (dd == node) {
                    int s = is64 ? (int)((const long long*)edges_raw)[e]
                                 : ((const int*)edges_raw)[e];
                    s = min(max(s, 0), Nn - 1);
                    unsigned v0 = *(const unsigned*)(AGG + (size_t)s * 384 + 256 + c2);
                    float ax = bf2f((unsigned short)(v0 & 0xffff));
                    float ay = bf2f((unsigned short)(v0 >> 16));
                    sx += ax; sy += ay;
                    mx = fmaxf(mx, ax); my = fmaxf(my, ay);
                    d++;
                }
            }
            if (d == 0) { mx = 0.f; my = 0.f; }
            unsigned short* row = AGG + (size_t)node * 384;
            *(unsigned*)(row + c2) = (unsigned)f2bf(sx) | ((unsigned)f2bf(sy) << 16);
            *(unsigned*)(row + 128 + c2) = (unsigned)f2bf(mx) | ((unsigned)f2bf(my) << 16);
        }
    }
}

// ---------------------------------------------------------------------------
// bf16 MFMA GEMM, 128x128 tile, 4 waves, 4x4 of 16x16x32 MFMA.
// Non-AFFINE path: counted-vmcnt pipeline (T4) — raw s_barrier, 2-deep
//   stage-ahead via global_load_lds; next tile's 4 loads stay in flight
//   across the barrier (never vmcnt(0) mid-loop).
// AFFINE path: reg-staged A (BN1 transform) + __syncthreads (proven).
// GRU epilogue uses fast exp2/rcp sigmoid+tanh.
// ---------------------------------------------------------------------------
template <int AFFINE, int LEAKY, int STATS, int GRUE>
__global__ __launch_bounds__(256) void k_mgemm(
    const unsigned short* __restrict__ A, int lda,
    const unsigned short* __restrict__ Bt,
    const float* __restrict__ bias,
    const float* __restrict__ sumA, const float* __restrict__ sqA,
    const float* __restrict__ gA, const float* __restrict__ beA,
    unsigned short* __restrict__ Cb, int ldc,
    int M, int K, float* __restrict__ sumO, float* __restrict__ sqO, float invN,
    const unsigned short* __restrict__ Xb) {
    __shared__ unsigned short ABs[2][2][4096];  // [buf][A|B][128*32]
    __shared__ float sc1[256], sh1[256];
    __shared__ float ssum[128], ssq[128];
    unsigned short* RP = &ABs[0][0][0];         // epilogue repack region

    const int t = threadIdx.x;
    const int lane = t & 63;
    const int wave = t >> 6;
    const int wr = (wave >> 1) * 64;
    const int wc = (wave & 1) * 64;
    const int quad = lane >> 4;
    const int l16 = lane & 15;
    const int sig = (l16 >> 1) & 3;             // fragment-read swizzle

    // XCD-grouped bijective remap (m204)
    const int ncb = gridDim.x;
    const int nwg = ncb * gridDim.y;
    int lin = blockIdx.y * ncb + blockIdx.x;
    const int qq = nwg >> 3, rr = nwg & 7;
    const int xcd = lin & 7, pos = lin >> 3;
    const int nl = (xcd < rr ? xcd * (qq + 1) : rr * (qq + 1) + (xcd - rr) * qq) + pos;
    const int j0 = (nl % ncb) * 128;
    const int r0 = (nl / ncb) * 128;

    if (AFFINE) {
        float m = sumA[t] * invN;
        float v = sqA[t] * invN - m * m;
        if (v < 0.f) v = 0.f;
        float rs = rsqrtf(v + 1e-5f);
        float sc = gA[t] * rs;
        sc1[t] = sc;
        sh1[t] = beA[t] - m * sc;
    }
    if (STATS && t < 128) { ssum[t] = 0.f; ssq[t] = 0.f; }
    if (AFFINE || STATS) __syncthreads();

    f32x4 acc[4][4];
#pragma unroll
    for (int i = 0; i < 4; i++)
#pragma unroll
        for (int j = 0; j < 4; j++) acc[i][j] = (f32x4){0.f, 0.f, 0.f, 0.f};

    // staging geometry: call (wave,p) covers rows [(2w+p)*16, +16)
    const int rowl = lane >> 2;
    const int gsw8 = (((lane & 3) ^ ((lane >> 3) & 3))) * 8;

    // AFFINE reg-staging geometry (writes same swizzled layout)
    const int srow = t >> 2;
    const int sg8 = (t & 3) * 8;
    const int swz8 = (((t & 3) ^ ((t >> 3) & 3))) * 8;
    float4 areg[2];

    auto stageA = [&](int buf, int k0) {
#pragma unroll
        for (int p = 0; p < 2; p++) {
            int row = (wave * 2 + p) * 16 + rowl;
            int gr = r0 + row;
            if (gr >= M) gr = M - 1;
            gld16(A + (size_t)gr * lda + k0 + gsw8,
                  &ABs[buf][0][(wave * 2 + p) * 512]);
        }
    };
    auto stageB = [&](int buf, int k0) {
#pragma unroll
        for (int p = 0; p < 2; p++) {
            int row = (wave * 2 + p) * 16 + rowl;
            gld16(Bt + (size_t)(j0 + row) * K + k0 + gsw8,
                  &ABs[buf][1][(wave * 2 + p) * 512]);
        }
    };
    auto loadA = [&](int k0) {
#pragma unroll
        for (int p = 0; p < 2; p++) {
            int gr = r0 + p * 64 + srow;
            areg[p] = make_float4(0.f, 0.f, 0.f, 0.f);
            if (gr < M) areg[p] = *(const float4*)(A + (size_t)gr * lda + k0 + sg8);
        }
    };
    auto writeA = [&](int buf, int k0) {
        union U8 { float4 f; unsigned short u[8]; } uv;
#pragma unroll
        for (int p = 0; p < 2; p++) {
            uv.f = areg[p];
#pragma unroll
            for (int q = 0; q < 8; q++) {
                float f = bf2f(uv.u[q]) * sc1[k0 + sg8 + q] + sh1[k0 + sg8 + q];
                uv.u[q] = f2bf(f);
            }
            *(float4*)&ABs[buf][0][(p * 64 + srow) * 32 + swz8] = uv.f;
        }
    };

    if (!AFFINE) {
        // ---- counted-vmcnt pipeline: 2 tiles staged ahead, never drain to 0 ----
        stageA(0, 0); stageB(0, 0);
        if (32 < K) { stageA(1, 32); stageB(1, 32); }
        for (int k0 = 0; k0 < K; k0 += 32) {
            const int cur = (k0 >> 5) & 1;
            if (k0 + 32 < K)
                asm volatile("s_waitcnt vmcnt(4)\n\ts_barrier" ::: "memory");
            else
                asm volatile("s_waitcnt vmcnt(0)\n\ts_barrier" ::: "memory");
            bf16x8 af[4], bfr[4];
#pragma unroll
            for (int i = 0; i < 4; i++) {
                af[i]  = *(bf16x8*)&ABs[cur][0][(wr + i * 16 + l16) * 32 + (quad ^ sig) * 8];
                bfr[i] = *(bf16x8*)&ABs[cur][1][(wc + i * 16 + l16) * 32 + (quad ^ sig) * 8];
            }
            asm volatile("s_waitcnt lgkmcnt(0)\n\ts_barrier" ::: "memory");
            if (k0 + 64 < K) { stageA(cur, k0 + 64); stageB(cur, k0 + 64); }
#pragma unroll
            for (int mt = 0; mt < 4; mt++)
#pragma unroll
                for (int nt = 0; nt < 4; nt++)
                    acc[mt][nt] = __builtin_amdgcn_mfma_f32_16x16x32_bf16(
                        af[mt], bfr[nt], acc[mt][nt], 0, 0, 0);
        }
    } else {
        // ---- AFFINE: reg-staged A + __syncthreads double-buffer (proven) ----
        loadA(0); writeA(0, 0);
        stageB(0, 0);
        __syncthreads();
        int buf = 0;
        for (int k0 = 0; k0 < K; k0 += 32) {
            const int kn = k0 + 32;
            const bool hasNext = kn < K;
            if (hasNext) {
                loadA(kn);
                stageB(buf ^ 1, kn);
            }
            bf16x8 af[4], bfr[4];
#pragma unroll
            for (int i = 0; i < 4; i++) {
                af[i]  = *(bf16x8*)&ABs[buf][0][(wr + i * 16 + l16) * 32 + (quad ^ sig) * 8];
                bfr[i] = *(bf16x8*)&ABs[buf][1][(wc + i * 16 + l16) * 32 + (quad ^ sig) * 8];
            }
#pragma unroll
            for (int mt = 0; mt < 4; mt++)
#pragma unroll
                for (int nt = 0; nt < 4; nt++)
                    acc[mt][nt] = __builtin_amdgcn_mfma_f32_16x16x32_bf16(
                        af[mt], bfr[nt], acc[mt][nt], 0, 0, 0);
            if (hasNext) writeA(buf ^ 1, kn);
            __syncthreads();
            buf ^= 1;
        }
    }

    if (GRUE) {
        // ---- GRU epilogue: nt=gate (0:r 1:z 2:i_n 3:h_n), dim = dimb+l16 ----
        const int dimb = (j0 + wc) >> 2;       // global hidden-dim base for wave
        const int dloc = (wc >> 2) + l16;      // 0..31 block-local dim
        const float bR = bias[j0 + wc + l16];
        const float bZ = bias[j0 + wc + 16 + l16];
        const float bI = bias[j0 + wc + 32 + l16];
        const float bH = bias[j0 + wc + 48 + l16];
#pragma unroll
        for (int mt = 0; mt < 4; mt++) {
#pragma unroll
            for (int reg = 0; reg < 4; reg++) {
                int rloc = wr + mt * 16 + quad * 4 + reg;
                int grow = r0 + rloc;
                int gi = grow < M ? grow : M - 1;
                float r = fsigm(acc[mt][0][reg] + bR);
                float z = fsigm(acc[mt][1][reg] + bZ);
                float nn = ftanh(acc[mt][2][reg] + bI + r * (acc[mt][3][reg] + bH));
                float xv = bf2f(Xb[(size_t)gi * 384 + 256 + dimb + l16]);
                float h = (1.0f - z) * nn + z * xv;
                RP[rloc * 40 + dloc] = f2bf(h);
            }
        }
        __syncthreads();
#pragma unroll
        for (int p = 0; p < 2; p++) {
            int id = p * 256 + t;              // 0..511 = 128 rows x 4 chunks
            int rloc = id >> 2, ck = id & 3;
            int grow = r0 + rloc;
            if (grow < M)
                *(float4*)(Cb + (size_t)grow * ldc + (j0 >> 2) + ck * 8) =
                    *(const float4*)&RP[rloc * 40 + ck * 8];
        }
        return;
    }

    // ---- standard epilogue: repack via LDS, coalesced 16B stores ----
#pragma unroll
    for (int half = 0; half < 2; half++) {
        if (wr == half * 64) {
#pragma unroll
            for (int nt = 0; nt < 4; nt++) {
                int colLoc = wc + nt * 16 + l16;
                float bv = bias[j0 + colLoc];
                float s = 0.f, q = 0.f;
#pragma unroll
                for (int mt = 0; mt < 4; mt++) {
#pragma unroll
                    for (int reg = 0; reg < 4; reg++) {
                        int rloc = mt * 16 + quad * 4 + reg;
                        float v = acc[mt][nt][reg] + bv;
                        if (LEAKY) v = (v >= 0.f) ? v : 0.01f * v;
                        if (STATS && (r0 + half * 64 + rloc) < M) { s += v; q += v * v; }
                        RP[rloc * 128 + colLoc] = f2bf(v);
                    }
                }
                if (STATS) {
                    atomicAdd(&ssum[colLoc], s);
                    atomicAdd(&ssq[colLoc], q);
                }
            }
        }
        __syncthreads();
#pragma unroll
        for (int p = 0; p < 4; p++) {
            int id = p * 256 + t;      // 0..1023 = 64 rows x 16 chunks
            int rloc = id >> 4;
            int ck = id & 15;
            int grow = r0 + half * 64 + rloc;
            if (grow < M)
                *(float4*)(Cb + (size_t)grow * ldc + j0 + ck * 8) =
                    *(const float4*)&RP[rloc * 128 + ck * 8];
        }
        __syncthreads();
    }
    if (STATS && t < 128) {
        atomicAdd(&sumO[j0 + t], ssum[t]);
        atomicAdd(&sqO[j0 + t], ssq[t]);
    }
}

// out(fp32) = bf2f(ypre)*scale2 + shift2 (BN2 finalize inline), 4 elems/thread
__global__ void k_affine2(const unsigned short* __restrict__ ypre, float* __restrict__ out,
                          const float* __restrict__ sum2, const float* __restrict__ sq2,
                          const float* __restrict__ g2, const float* __restrict__ be2,
                          int total4, float invN) {
    __shared__ float sc[128], sh[128];
    int t = threadIdx.x;
    if (t < 128) {
        float m = sum2[t] * invN;
        float v = sq2[t] * invN - m * m;
        if (v < 0.f) v = 0.f;
        float rs = rsqrtf(v + 1e-5f);
        float s = g2[t] * rs;
        sc[t] = s;
        sh[t] = be2[t] - m * s;
    }
    __syncthreads();
    int idx = blockIdx.x * 256 + t;
    if (idx >= total4) return;
    int i4 = idx * 4;
    int c = i4 & 127;
    unsigned u0 = *(const unsigned*)(ypre + i4);
    unsigned u1 = *(const unsigned*)(ypre + i4 + 2);
    float4 o;
    o.x = bf2f((unsigned short)(u0 & 0xffff)) * sc[c]     + sh[c];
    o.y = bf2f((unsigned short)(u0 >> 16))    * sc[c + 1] + sh[c + 1];
    o.z = bf2f((unsigned short)(u1 & 0xffff)) * sc[c + 2] + sh[c + 2];
    o.w = bf2f((unsigned short)(u1 >> 16))    * sc[c + 3] + sh[c + 3];
    *(float4*)(out + i4) = o;
}

// ---------------------------------------------------------------------------
extern "C" void kernel_launch(void* const* d_in, const int* in_sizes, int n_in,
                              void* d_out, int out_size, void* d_ws, size_t ws_size,
                              hipStream_t stream) {
    const float* x       = (const float*)d_in[0];
    const void*  edges   = d_in[1];
    const float* W_merge = (const float*)d_in[2];
    const float* b_merge = (const float*)d_in[3];
    const float* W_ih    = (const float*)d_in[4];
    const float* W_hh    = (const float*)d_in[5];
    const float* b_ih    = (const float*)d_in[6];
    const float* b_hh    = (const float*)d_in[7];
    const float* W1      = (const float*)d_in[8];
    const float* b1      = (const float*)d_in[9];
    const float* g1      = (const float*)d_in[10];
    const float* be1     = (const float*)d_in[11];
    const float* W2      = (const float*)d_in[12];
    const float* b2      = (const float*)d_in[13];
    const float* g2      = (const float*)d_in[14];
    const float* be2     = (const float*)d_in[15];

    const int N = in_sizes[0] / DD;
    const int E = in_sizes[1] / 2;
    float* out = (float*)d_out;

    size_t need = ((size_t)640 * N + 120000) * sizeof(float);
    if (ws_size < need) {
        k_wsfail<<<(out_size + 255) / 256, 256, 0, stream>>>(
            out, (float)(ws_size >> 20), out_size);
        return;
    }

    const int NB = (N + 63) >> 6;   // 64-node buckets

    float* ws = (float*)d_ws;
    // [0,192N): AGG bf16 Nx384 (sum|max|x) -> later y1b bf16 Nx256 at [0,128N),
    //                                         ypre bf16 Nx128 at [128N,192N)
    // [448N,512N): h bf16 Nx128
    // [512N,...): binned (NB*CAPB uints) + gCur + weights + sums
    unsigned short* AGG  = (unsigned short*)ws;
    unsigned short* y1b  = (unsigned short*)ws;
    unsigned short* ypre = (unsigned short*)(ws + (size_t)128 * N);
    unsigned short* hb16 = (unsigned short*)(ws + (size_t)448 * N);

    unsigned* binned = (unsigned*)(ws + (size_t)512 * N);
    int* gCur = (int*)(binned + (size_t)NB * CAPB);

    float* wbase = (float*)(gCur + NB + 64);
    unsigned short* BtG = (unsigned short*)wbase;                 // 512*384 el
    unsigned short* w1T = (unsigned short*)(wbase + 98304);       // 32768 el
    unsigned short* w2T = (unsigned short*)(wbase + 98304 + 16384);
    float* biasG = wbase + 98304 + 32768;   // 512
    float* sums  = biasG + 512;             // 768
    float* sum1 = sums, *sq1 = sums + 256, *sum2 = sums + 512, *sq2 = sums + 640;
    int*   flag  = (int*)(sums + 768);

    const int nrb  = (N + 127) / 128;
    const int ncvt4 = (N * 32 + 255) / 256;
    const float invN = 1.0f / (float)N;

    // 1. setup (detect, zeros, w1T/w2T, x->AGG)
    k_setup<<<264 + ncvt4, 256, 0, stream>>>(
        (const int*)edges, flag, sums, gCur, NB, W1, W2, w1T, w2T, x, AGG, N * 32);
    // 2. fused gate weights, gate-permuted columns (fp32 dot, one bf16 rounding)
    k_fusew<<<512, 256, 0, stream>>>(W_merge, W_ih, W_hh, b_merge, b_ih, b_hh, BtG, biasG);
    // 3. bin edges
    k_bin<<<(E + 4095) / 4096, 256, 0, stream>>>(edges, flag, gCur, binned, E, N, NB);
    // 4. per-bucket aggregate -> AGG cols 0..255
    k_bagg<<<NB, 256, 0, stream>>>(binned, gCur, edges, flag, AGG, E, N);
    // 5. fused G2'+GRU: h = GRU(AGG @ BtG + biasG, x)  (K=384, F=512 -> 128)
    k_mgemm<0, 0, 0, 1><<<dim3(4, nrb), 256, 0, stream>>>(
        AGG, 384, BtG, biasG, nullptr, nullptr, nullptr, nullptr,
        hb16, 128, N, 384, nullptr, nullptr, invN, AGG);
    // 6. G4: y1b = leaky(h @ w1T + b1) + stats1  (K=128, F=256)
    k_mgemm<0, 1, 1, 0><<<dim3(2, nrb), 256, 0, stream>>>(
        hb16, 128, w1T, b1, nullptr, nullptr, nullptr, nullptr,
        y1b, 256, N, 128, sum1, sq1, invN, nullptr);
    // 7. G5: ypre = leaky(bn1(y1b) @ w2T + b2) + stats2  (K=256, F=128)
    k_mgemm<1, 1, 1, 0><<<dim3(1, nrb), 256, 0, stream>>>(
        y1b, 256, w2T, b2, sum1, sq1, g1, be1,
        ypre, 128, N, 256, sum2, sq2, invN, nullptr);
    // 8. BN2 finalize + affine -> fp32 out (4 elems/thread)
    k_affine2<<<ncvt4, 256, 0, stream>>>(ypre, out, sum2, sq2, g2, be2, N * 32, invN);
}